// Round 2
// baseline (170.428 us; speedup 1.0000x reference)
//
#include <hip/hip_runtime.h>
#include <hip/hip_bf16.h>
#include <math.h>

// Problem constants
#define B_     4
#define N_     2048
#define H_     256
#define R3     24      // 3*R
#define H3     768     // 3*H
#define NHEADS 4
#define DH     64
#define ROWS   8192    // B_*N_
#define EPS_   1e-8f
#define REGW   1e-5f
#define OUT_MAIN (ROWS*H_)   // 2097152

// Workspace layout (float offsets). Total ~28.4 MB.
#define QF_OFF  0
#define KF_OFF  (ROWS*H_)            // 2097152
#define V_OFF   (2*ROWS*H_)          // 4194304
#define Z_OFF   (3*ROWS*H_)          // 6291456  (ROWS*4 floats, stores 1/(sum+eps))
#define KVP_OFF (Z_OFF + ROWS*4)     // 6324224  (256*4096 floats: per-(b,h,chunk) partial kv)
#define KVT_OFF (KVP_OFF + 256*4096) // 7372800  (16*4096 floats: kv transposed [bh][e*64+d])

static __device__ __forceinline__ float elu1(float x) {
    return x > 0.f ? x + 1.f : expf(x);
}

// ---------------------------------------------------------------------------
// K_A: per 32-row block: qkv_low = x@w_low^T + b_low (in LDS), then
// qkv = qkv_low@w_high^T + b_high, split into qf/kf/v with elu+1 feature map,
// accumulate z = sum_d kf per head. Writes qf, kf, v, z(=reciprocal) to ws.
// Grid: 256 blocks x 256 threads.
// ---------------------------------------------------------------------------
__global__ __launch_bounds__(256) void ka_qkv(
    const float* __restrict__ x, const float* __restrict__ w_low,
    const float* __restrict__ b_low, const float* __restrict__ w_high,
    const float* __restrict__ b_high, float* __restrict__ ws)
{
    __shared__ float xs[32 * 260];   // x tile, padded stride 260 (bank-friendly)
    __shared__ float wls[24 * 260];  // w_low tile
    __shared__ float qls[32 * 28];   // qkv_low tile, stride 28 (16B aligned)
    __shared__ float zs[32 * 4];

    const int t = threadIdx.x;
    const int blk = blockIdx.x;
    const int rowbase = blk * 32;

    // stage x tile: 32x256 floats (2048 float4), 8 per thread, coalesced
    {
        const float4* xg = (const float4*)(x + (long)rowbase * H_);
#pragma unroll
        for (int i = 0; i < 8; i++) {
            int e4 = t + i * 256;
            float4 val = xg[e4];
            int e = e4 * 4;
            int r = e >> 8, k = e & 255;
            *(float4*)&xs[r * 260 + k] = val;
        }
    }
    // stage w_low: 24x256 floats (1536 float4), 6 per thread
    {
        const float4* wg = (const float4*)w_low;
#pragma unroll
        for (int i = 0; i < 6; i++) {
            int e4 = t + i * 256;
            float4 val = wg[e4];
            int e = e4 * 4;
            int r = e >> 8, k = e & 255;
            *(float4*)&wls[r * 260 + k] = val;
        }
    }
    // init qkv_low accumulators with bias; zero z accumulators
    for (int idx = t; idx < 32 * 24; idx += 256) {
        int r = idx / 24, j = idx - r * 24;
        qls[r * 28 + j] = b_low[j];
    }
    if (t < 128) zs[t] = 0.f;
    __syncthreads();

    // phase b: qkv_low[r][j] += sum_k x[r][k]*w_low[j][k]  (k-split by wave)
    {
        const int jg = t & 7;          // 8 j-groups
        const int rg = (t >> 3) & 7;   // 8 row-groups (rows rg+8m)
        const int kq = t >> 6;         // wave id = k quarter
        float acc[4][3] = {};
        const int k0 = kq * 64;
        for (int kk = 0; kk < 16; kk++) {
            int k = k0 + kk * 4;
            float4 xq[4], wq[3];
#pragma unroll
            for (int m = 0; m < 4; m++) xq[m] = *(const float4*)&xs[(rg + 8 * m) * 260 + k];
#pragma unroll
            for (int jj = 0; jj < 3; jj++) wq[jj] = *(const float4*)&wls[(jg + 8 * jj) * 260 + k];
#pragma unroll
            for (int m = 0; m < 4; m++)
#pragma unroll
                for (int jj = 0; jj < 3; jj++)
                    acc[m][jj] += xq[m].x * wq[jj].x + xq[m].y * wq[jj].y
                                + xq[m].z * wq[jj].z + xq[m].w * wq[jj].w;
        }
#pragma unroll
        for (int m = 0; m < 4; m++)
#pragma unroll
            for (int jj = 0; jj < 3; jj++)
                atomicAdd(&qls[(rg + 8 * m) * 28 + (jg + 8 * jj)], acc[m][jj]);
    }
    __syncthreads();

    // phase c: qkv[row][j] = b_high[j] + sum_{k<24} qkv_low[row][k]*w_high[j][k]
    // then split q/k/v, apply elu+1, store, accumulate z.
    {
        const int tr = t & 15, rr = t >> 4;
        const int r0 = rr, r1 = rr + 16;
        float4 q0[6], q1[6];
#pragma unroll
        for (int i = 0; i < 6; i++) {
            q0[i] = *(const float4*)&qls[r0 * 28 + i * 4];
            q1[i] = *(const float4*)&qls[r1 * 28 + i * 4];
        }
        float zp0[4] = {0.f, 0.f, 0.f, 0.f}, zp1[4] = {0.f, 0.f, 0.f, 0.f};
        float* qf = ws + QF_OFF;
        float* kf = ws + KF_OFF;
        float* vv = ws + V_OFF;
        const long row0 = rowbase + r0, row1 = rowbase + r1;
        for (int c = 0; c < 48; c++) {
            int j = tr + 16 * c;
            const float4* wj = (const float4*)(w_high + j * 24);
            float bh = b_high[j];
            float a0 = bh, a1 = bh;
#pragma unroll
            for (int i = 0; i < 6; i++) {
                float4 w4 = wj[i];
                a0 += q0[i].x * w4.x + q0[i].y * w4.y + q0[i].z * w4.z + q0[i].w * w4.w;
                a1 += q1[i].x * w4.x + q1[i].y * w4.y + q1[i].z * w4.z + q1[i].w * w4.w;
            }
            if (j < 256) {
                qf[row0 * H_ + j] = elu1(a0);
                qf[row1 * H_ + j] = elu1(a1);
            } else if (j < 512) {
                int jj = j - 256;
                float f0 = elu1(a0), f1 = elu1(a1);
                kf[row0 * H_ + jj] = f0;
                kf[row1 * H_ + jj] = f1;
                int h = jj >> 6;
                zp0[h] += f0;
                zp1[h] += f1;
            } else {
                int jj = j - 512;
                vv[row0 * H_ + jj] = a0;
                vv[row1 * H_ + jj] = a1;
            }
        }
#pragma unroll
        for (int h = 0; h < 4; h++) {
            atomicAdd(&zs[r0 * 4 + h], zp0[h]);
            atomicAdd(&zs[r1 * 4 + h], zp1[h]);
        }
    }
    __syncthreads();
    if (t < 128) {
        int r = t >> 2, h = t & 3;
        float* zg = ws + Z_OFF;
        zg[(long)(rowbase + r) * 4 + h] = 1.f / (zs[r * 4 + h] + EPS_);
    }
}

// ---------------------------------------------------------------------------
// K3: partial kv[b][h][d][e] = sum over 128-row chunk of kf[n][d]*v[n][e].
// Grid: 256 blocks (b*64 + h*16 + chunk) x 256 threads; thread = 4x4 tile.
// ---------------------------------------------------------------------------
__global__ __launch_bounds__(256) void k3_kv(
    const float* __restrict__ kf, const float* __restrict__ v,
    float* __restrict__ kvp)
{
    const int blk = blockIdx.x;
    const int chunk = blk & 15, h = (blk >> 4) & 3, b = blk >> 6;
    const int t = threadIdx.x;
    const int td = t >> 4, te = t & 15;
    const int d0 = td * 4, e0 = te * 4;
    float acc[4][4] = {};
    const long base = (long)b * N_ + chunk * 128;
    const float* kfp = kf + base * H_ + h * DH + d0;
    const float* vp  = v  + base * H_ + h * DH + e0;
    for (int i = 0; i < 128; i++) {
        float4 k4 = *(const float4*)(kfp + (long)i * H_);
        float4 v4 = *(const float4*)(vp  + (long)i * H_);
        float kk[4] = {k4.x, k4.y, k4.z, k4.w};
        float vv[4] = {v4.x, v4.y, v4.z, v4.w};
#pragma unroll
        for (int dd = 0; dd < 4; dd++)
#pragma unroll
            for (int ee = 0; ee < 4; ee++)
                acc[dd][ee] += kk[dd] * vv[ee];
    }
    float* outp = kvp + (long)blk * 4096;
#pragma unroll
    for (int dd = 0; dd < 4; dd++) {
        float4 st = {acc[dd][0], acc[dd][1], acc[dd][2], acc[dd][3]};
        *(float4*)(outp + (d0 + dd) * 64 + e0) = st;
    }
}

// ---------------------------------------------------------------------------
// K3b: reduce 16 chunk-partials -> kv_t[bh][e*64+d] (transposed for K4).
// Also writes the constant attn_reg_loss = REGW/N (softmax rows sum to 1,
// so mean(|attn|) == 1/N identically; adj_u/adj_v/q/k cannot change it).
// Grid: 64 blocks x 256 threads.
// ---------------------------------------------------------------------------
__global__ __launch_bounds__(256) void k3b_reduce(
    const float* __restrict__ kvp, float* __restrict__ kvt,
    float* __restrict__ out)
{
    const int blk = blockIdx.x;
    const int t = threadIdx.x;
    const int bh = blk >> 2;
    const int base = (blk & 3) * 1024;
#pragma unroll
    for (int i = 0; i < 4; i++) {
        int idx = base + i * 256 + t;   // idx = d*64+e, coalesced reads
        float s = 0.f;
#pragma unroll
        for (int c = 0; c < 16; c++)
            s += kvp[((long)bh * 16 + c) * 4096 + idx];
        int d = idx >> 6, e = idx & 63;
        kvt[(long)bh * 4096 + e * 64 + d] = s;
    }
    if (blk == 0 && t == 0)
        out[OUT_MAIN] = REGW / (float)N_;   // 4.8828125e-9, fp32
}

// ---------------------------------------------------------------------------
// K4: per 32-row block: lin[row][h*64+e] = z[row][h]*sum_d qf[row][h*64+d]*kv[d][e]
// then low = lin@w_out_low^T + b, out = low@w_out_high^T + b -> fp32.
// Grid: 256 blocks x 256 threads.
// ---------------------------------------------------------------------------
__global__ __launch_bounds__(256) void k4_out(
    const float* __restrict__ ws,
    const float* __restrict__ w_out_low, const float* __restrict__ b_out_low,
    const float* __restrict__ w_out_high, const float* __restrict__ b_out_high,
    float* __restrict__ out)
{
    __shared__ float kvs[4 * 64 * 68];  // [h][e][stride 68] -> 69.6 KB, <=2-way conflicts
    __shared__ float lin[32 * 260];
    __shared__ float low[32 * 8];

    const int t = threadIdx.x;
    const int blk = blockIdx.x;
    const int rowbase = blk * 32;
    const int b = blk >> 6;

    // stage kv_t for this batch: 4*4096 floats
    {
        const float* kvt = ws + KVT_OFF + (long)b * 4 * 4096;
#pragma unroll
        for (int i = 0; i < 16; i++) {
            int g = (t + i * 256) * 4;
            float4 val = *(const float4*)(kvt + g);
            int h = g >> 12, rem = g & 4095;
            int e = rem >> 6, d = rem & 63;
            *(float4*)&kvs[(h * 64 + e) * 68 + d] = val;
        }
    }
    __syncthreads();

    const float* qf = ws + QF_OFF;
    const float* zg = ws + Z_OFF;
    {
        const int tr = t & 15, rr = t >> 4;
        const long r0g = rowbase + rr, r1g = rowbase + rr + 16;
        float acc0[16] = {}, acc1[16] = {};
#pragma unroll
        for (int h = 0; h < 4; h++) {
            const float* q0p = qf + r0g * H_ + h * DH;
            const float* q1p = qf + r1g * H_ + h * DH;
            for (int dq = 0; dq < 16; dq++) {
                float4 qa = *(const float4*)(q0p + dq * 4);
                float4 qb = *(const float4*)(q1p + dq * 4);
#pragma unroll
                for (int cl = 0; cl < 4; cl++) {
                    int e = tr + 16 * cl;
                    float4 kv4 = *(const float4*)&kvs[(h * 64 + e) * 68 + dq * 4];
                    acc0[h * 4 + cl] += qa.x * kv4.x + qa.y * kv4.y + qa.z * kv4.z + qa.w * kv4.w;
                    acc1[h * 4 + cl] += qb.x * kv4.x + qb.y * kv4.y + qb.z * kv4.z + qb.w * kv4.w;
                }
            }
        }
#pragma unroll
        for (int cc = 0; cc < 16; cc++) {
            int h = cc >> 2;
            int j = tr + 16 * cc;
            lin[rr * 260 + j]        = acc0[cc] * zg[r0g * 4 + h];
            lin[(rr + 16) * 260 + j] = acc1[cc] * zg[r1g * 4 + h];
        }
    }
    __syncthreads();

    // low projection: low[r][j] = b_out_low[j] + sum_k lin[r][k]*w_out_low[j][k]
    {
        const int r = t >> 3, j = t & 7;
        float a = b_out_low[j];
        const float4* wj = (const float4*)(w_out_low + j * H_);
        for (int kq = 0; kq < 64; kq++) {
            float4 l4 = *(const float4*)&lin[r * 260 + kq * 4];
            float4 w4 = wj[kq];
            a += l4.x * w4.x + l4.y * w4.y + l4.z * w4.z + l4.w * w4.w;
        }
        low[r * 8 + j] = a;
    }
    __syncthreads();

    // final: out[row][i] = b_out_high[i] + sum_j low[r][j]*w_out_high[i][j]
    // fp32 output, float4 stores (16B coalesced).
    {
        const int r = t >> 3, ig = t & 7;
        float l[8];
#pragma unroll
        for (int j = 0; j < 8; j++) l[j] = low[r * 8 + j];
        float* outp = out + (long)(rowbase + r) * H_;
        for (int i2 = 0; i2 < 8; i2++) {
            int i = ig * 32 + i2 * 4;
            const float* wh = w_out_high + i * 8;   // rows i..i+3, 8 floats each
            float4 s;
            s.x = b_out_high[i + 0];
            s.y = b_out_high[i + 1];
            s.z = b_out_high[i + 2];
            s.w = b_out_high[i + 3];
#pragma unroll
            for (int j = 0; j < 8; j++) {
                s.x += l[j] * wh[j];
                s.y += l[j] * wh[8 + j];
                s.z += l[j] * wh[16 + j];
                s.w += l[j] * wh[24 + j];
            }
            *(float4*)(outp + i) = s;
        }
    }
}

extern "C" void kernel_launch(void* const* d_in, const int* in_sizes, int n_in,
                              void* d_out, int out_size, void* d_ws, size_t ws_size,
                              hipStream_t stream) {
    const float* x          = (const float*)d_in[0];
    const float* w_qkv_low  = (const float*)d_in[1];
    const float* b_qkv_low  = (const float*)d_in[2];
    const float* w_qkv_high = (const float*)d_in[3];
    const float* b_qkv_high = (const float*)d_in[4];
    const float* w_out_low  = (const float*)d_in[5];
    const float* b_out_low  = (const float*)d_in[6];
    const float* w_out_high = (const float*)d_in[7];
    const float* b_out_high = (const float*)d_in[8];
    // d_in[9] adj_u, d_in[10] adj_v: only affect attn_reg_loss via softmax,
    // whose rows sum to 1 regardless -> loss is the constant REGW/N. Unused.
    float* ws = (float*)d_ws;
    float* out = (float*)d_out;

    ka_qkv<<<256, 256, 0, stream>>>(x, w_qkv_low, b_qkv_low, w_qkv_high, b_qkv_high, ws);
    k3_kv<<<256, 256, 0, stream>>>(ws + KF_OFF, ws + V_OFF, ws + KVP_OFF);
    k3b_reduce<<<64, 256, 0, stream>>>(ws + KVP_OFF, ws + KVT_OFF, out);
    k4_out<<<256, 256, 0, stream>>>(ws, w_out_low, b_out_low, w_out_high, b_out_high, out);
}

// Round 3
// 154.790 us; speedup vs baseline: 1.1010x; 1.1010x over previous
//
#include <hip/hip_runtime.h>
#include <hip/hip_bf16.h>
#include <math.h>

// Problem constants
#define B_     4
#define N_     2048
#define H_     256
#define NHEADS 4
#define DH     64
#define ROWS   8192    // B_*N_
#define EPS_   1e-8f
#define REGW   1e-5f
#define OUT_MAIN (ROWS*H_)   // 2097152

// Workspace layout (float offsets). Total ~34 MB.
#define QF_OFF  0
#define KF_OFF  (ROWS*H_)             // 2097152
#define V_OFF   (2*ROWS*H_)           // 4194304
#define Z_OFF   (3*ROWS*H_)           // 6291456  (ROWS*4, stores 1/(sum+eps))
#define KVP_OFF (Z_OFF + ROWS*4)      // 6324224  (512*4096: per-(b,h,chunk) partial kv)
#define KVT_OFF (KVP_OFF + 512*4096)  // 8421376  (16*4096: kv transposed [bh][e*64+d])

static __device__ __forceinline__ float elu1(float x) {
    return x > 0.f ? x + 1.f : __expf(x);
}

// ---------------------------------------------------------------------------
// ka_fused: 512 blocks x 256 thr; block = 16 rows; wave = 4 rows.
// Per wave: lanes (rowgrp = lane>>4, tl = lane&15). Phase b: lane computes
// k-slice [tl*16, tl*16+16) partials of qkv_low[24], butterfly width-16 ->
// all lanes hold full qkv_low in 24 regs. Phase c: 3 chunks of 256 outputs;
// w_high chunk (24 KB) staged in LDS; lane computes j = c*256 + tl + 16*jj.
// elu+1 applied to q,k; z = per-head kf sum via width-16 butterfly.
// ---------------------------------------------------------------------------
__global__ __launch_bounds__(256) void ka_fused(
    const float* __restrict__ x, const float* __restrict__ w_low,
    const float* __restrict__ b_low, const float* __restrict__ w_high,
    const float* __restrict__ b_high, float* __restrict__ ws)
{
    __shared__ float wbuf[6240];   // w_low as [j][k] stride 260; reused for w_high chunks [256][24]

    const int t   = threadIdx.x;
    const int blk = blockIdx.x;
    const int lane = t & 63;
    const int rgrp = lane >> 4;
    const int tl   = lane & 15;
    const int wv   = t >> 6;
    const size_t row = (size_t)blk * 16 + wv * 4 + rgrp;

    // stage w_low [24][256] -> wbuf[j*260+k], coalesced f4
#pragma unroll
    for (int i = 0; i < 6; i++) {
        int g = t + i * 256;            // f4 index
        int e = g * 4;
        int j = e >> 8, k = e & 255;
        *(float4*)&wbuf[j * 260 + k] = *(const float4*)(w_low + e);
    }
    __syncthreads();

    // phase b: per-lane k-slice partials, butterfly-reduce width 16
    float ql[24];
    {
        float4 xr[4];
#pragma unroll
        for (int i = 0; i < 4; i++)
            xr[i] = *(const float4*)(x + row * H_ + tl * 16 + i * 4);
#pragma unroll
        for (int j = 0; j < 24; j++) {
            float s = 0.f;
#pragma unroll
            for (int i = 0; i < 4; i++) {
                float4 w4 = *(const float4*)&wbuf[j * 260 + tl * 16 + i * 4];
                s += xr[i].x * w4.x + xr[i].y * w4.y + xr[i].z * w4.z + xr[i].w * w4.w;
            }
            ql[j] = s;
        }
#pragma unroll
        for (int j = 0; j < 24; j++) {
            float s = ql[j];
            s += __shfl_xor(s, 1, 16);
            s += __shfl_xor(s, 2, 16);
            s += __shfl_xor(s, 4, 16);
            s += __shfl_xor(s, 8, 16);
            ql[j] = s + b_low[j];
        }
    }

    // phase c: three 256-output chunks (q, k, v)
    float* qf = ws + QF_OFF;
    float* kf = ws + KF_OFF;
    float* vv = ws + V_OFF;
    float* zg = ws + Z_OFF;
    for (int c = 0; c < 3; c++) {
        __syncthreads();   // all waves done reading wbuf (phase b / previous chunk)
        // stage w_high chunk c: rows [c*256, c*256+256), 24 floats each -> contiguous 24 KB
#pragma unroll
        for (int i = 0; i < 6; i++) {
            int g = (t + i * 256) * 4;
            *(float4*)&wbuf[g] = *(const float4*)(w_high + c * 6144 + g);
        }
        __syncthreads();

        float zp0 = 0.f, zp1 = 0.f, zp2 = 0.f, zp3 = 0.f;
#pragma unroll
        for (int jj = 0; jj < 16; jj++) {
            int jl = tl + 16 * jj;          // local row in chunk
            float a = b_high[c * 256 + jl];
#pragma unroll
            for (int i = 0; i < 6; i++) {
                float4 w4 = *(const float4*)&wbuf[jl * 24 + i * 4];
                a += ql[i * 4 + 0] * w4.x + ql[i * 4 + 1] * w4.y
                   + ql[i * 4 + 2] * w4.z + ql[i * 4 + 3] * w4.w;
            }
            size_t oidx = row * H_ + jl;
            if (c == 0) {
                qf[oidx] = elu1(a);
            } else if (c == 1) {
                float f = elu1(a);
                kf[oidx] = f;
                int hq = jj >> 2;
                if (hq == 0) zp0 += f; else if (hq == 1) zp1 += f;
                else if (hq == 2) zp2 += f; else zp3 += f;
            } else {
                vv[oidx] = a;
            }
        }
        if (c == 1) {
            float zh[4] = {zp0, zp1, zp2, zp3};
#pragma unroll
            for (int h = 0; h < 4; h++) {
                float s = zh[h];
                s += __shfl_xor(s, 1, 16);
                s += __shfl_xor(s, 2, 16);
                s += __shfl_xor(s, 4, 16);
                s += __shfl_xor(s, 8, 16);
                zh[h] = s;
            }
            if (tl < 4) {
                float sel = tl == 0 ? zh[0] : tl == 1 ? zh[1] : tl == 2 ? zh[2] : zh[3];
                zg[row * 4 + tl] = 1.f / (sel + EPS_);
            }
        }
    }
}

// ---------------------------------------------------------------------------
// k2_kv: partial kv over 64-row chunks. Grid 512 = (b,h,ch): blk = b*128+h*32+ch.
// LDS-staged kf/v slices (stride 68: conflict-free), 4x4 register tile.
// ---------------------------------------------------------------------------
__global__ __launch_bounds__(256) void k2_kv(
    const float* __restrict__ kf, const float* __restrict__ v,
    float* __restrict__ kvp)
{
    __shared__ float kfs[64 * 68];
    __shared__ float vss[64 * 68];
    const int blk = blockIdx.x;
    const int b = blk >> 7, h = (blk >> 5) & 3, ch = blk & 31;
    const int t = threadIdx.x;
    const size_t base = ((size_t)b * N_ + ch * 64) * H_ + h * DH;
#pragma unroll
    for (int i = 0; i < 4; i++) {
        int g = t + i * 256;
        int r = g >> 4, c4 = (g & 15) * 4;
        *(float4*)&kfs[r * 68 + c4] = *(const float4*)(kf + base + (size_t)r * H_ + c4);
        *(float4*)&vss[r * 68 + c4] = *(const float4*)(v  + base + (size_t)r * H_ + c4);
    }
    __syncthreads();
    const int d0 = (t >> 4) * 4, e0 = (t & 15) * 4;
    float a00=0,a01=0,a02=0,a03=0, a10=0,a11=0,a12=0,a13=0;
    float a20=0,a21=0,a22=0,a23=0, a30=0,a31=0,a32=0,a33=0;
    for (int i = 0; i < 64; i++) {
        float4 k4 = *(const float4*)&kfs[i * 68 + d0];
        float4 v4 = *(const float4*)&vss[i * 68 + e0];
        a00 += k4.x*v4.x; a01 += k4.x*v4.y; a02 += k4.x*v4.z; a03 += k4.x*v4.w;
        a10 += k4.y*v4.x; a11 += k4.y*v4.y; a12 += k4.y*v4.z; a13 += k4.y*v4.w;
        a20 += k4.z*v4.x; a21 += k4.z*v4.y; a22 += k4.z*v4.z; a23 += k4.z*v4.w;
        a30 += k4.w*v4.x; a31 += k4.w*v4.y; a32 += k4.w*v4.z; a33 += k4.w*v4.w;
    }
    float* outp = kvp + (size_t)blk * 4096;
    *(float4*)(outp + (d0 + 0) * 64 + e0) = make_float4(a00, a01, a02, a03);
    *(float4*)(outp + (d0 + 1) * 64 + e0) = make_float4(a10, a11, a12, a13);
    *(float4*)(outp + (d0 + 2) * 64 + e0) = make_float4(a20, a21, a22, a23);
    *(float4*)(outp + (d0 + 3) * 64 + e0) = make_float4(a30, a31, a32, a33);
}

// ---------------------------------------------------------------------------
// k2b: reduce 32 partials -> kv_t[bh][e*64+d]; write constant reg-loss.
// (softmax rows sum to 1 => mean|attn| == 1/N identically; adj_u/adj_v unused)
// Grid 256 x 256.
// ---------------------------------------------------------------------------
__global__ __launch_bounds__(256) void k2b_reduce(
    const float* __restrict__ kvp, float* __restrict__ kvt,
    float* __restrict__ out)
{
    const int blk = blockIdx.x, t = threadIdx.x;
    const int bh = blk >> 4;
    const int idx = (blk & 15) * 256 + t;   // idx = d*64+e
    float s = 0.f;
#pragma unroll
    for (int c = 0; c < 32; c++)
        s += kvp[((size_t)bh * 32 + c) * 4096 + idx];
    int d = idx >> 6, e = idx & 63;
    kvt[(size_t)bh * 4096 + e * 64 + d] = s;
    if (blk == 0 && t == 0)
        out[OUT_MAIN] = REGW / (float)N_;   // 4.8828125e-9
}

// ---------------------------------------------------------------------------
// k4_out: 512 blocks x 256 thr; block = 16 rows. kv staged per head (17.4 KB),
// lin = z * qf @ kv -> LDS, then low (r=8) and high projections, f4 stores.
// ---------------------------------------------------------------------------
__global__ __launch_bounds__(256) void k4_out(
    const float* __restrict__ ws,
    const float* __restrict__ w_out_low, const float* __restrict__ b_out_low,
    const float* __restrict__ w_out_high, const float* __restrict__ b_out_high,
    float* __restrict__ out)
{
    __shared__ float kvs[64 * 68];
    __shared__ float lin[16 * 260];
    __shared__ float lows[16 * 8];

    const int t = threadIdx.x, blk = blockIdx.x;
    const int rowbase = blk * 16;
    const int b = blk >> 7;
    const float* qf  = ws + QF_OFF;
    const float* zg  = ws + Z_OFF;
    const float* kvt = ws + KVT_OFF;
    const int r = t >> 4, tl = t & 15;
    const size_t row = rowbase + r;

    for (int h = 0; h < 4; h++) {
        __syncthreads();
        // stage kvs[e][d] from kvt (contiguous copy), stride 68
#pragma unroll
        for (int i = 0; i < 4; i++) {
            int g = t + i * 256;
            int e = g >> 4, c4 = (g & 15) * 4;
            *(float4*)&kvs[e * 68 + c4] =
                *(const float4*)(kvt + ((size_t)(b * 4 + h)) * 4096 + g * 4);
        }
        __syncthreads();
        const float* qp = qf + row * H_ + h * DH;
        float ac0 = 0.f, ac1 = 0.f, ac2 = 0.f, ac3 = 0.f;
        for (int dq = 0; dq < 16; dq++) {
            float4 qa = *(const float4*)(qp + dq * 4);
            float4 k0 = *(const float4*)&kvs[(tl * 4 + 0) * 68 + dq * 4];
            float4 k1 = *(const float4*)&kvs[(tl * 4 + 1) * 68 + dq * 4];
            float4 k2 = *(const float4*)&kvs[(tl * 4 + 2) * 68 + dq * 4];
            float4 k3 = *(const float4*)&kvs[(tl * 4 + 3) * 68 + dq * 4];
            ac0 += qa.x*k0.x + qa.y*k0.y + qa.z*k0.z + qa.w*k0.w;
            ac1 += qa.x*k1.x + qa.y*k1.y + qa.z*k1.z + qa.w*k1.w;
            ac2 += qa.x*k2.x + qa.y*k2.y + qa.z*k2.z + qa.w*k2.w;
            ac3 += qa.x*k3.x + qa.y*k3.y + qa.z*k3.z + qa.w*k3.w;
        }
        float zv = zg[row * 4 + h];
        *(float4*)&lin[r * 260 + h * DH + tl * 4] =
            make_float4(ac0 * zv, ac1 * zv, ac2 * zv, ac3 * zv);
    }
    __syncthreads();

    if (t < 128) {
        int rr = t >> 3, j = t & 7;
        float a = b_out_low[j];
        const float4* wj = (const float4*)(w_out_low + j * H_);
#pragma unroll
        for (int kq = 0; kq < 64; kq++) {
            float4 l4 = *(const float4*)&lin[rr * 260 + kq * 4];
            float4 w4 = wj[kq];
            a += l4.x * w4.x + l4.y * w4.y + l4.z * w4.z + l4.w * w4.w;
        }
        lows[rr * 8 + j] = a;
    }
    __syncthreads();

    {
        int rr = t >> 4, ig = t & 15;
        float l[8];
#pragma unroll
        for (int j = 0; j < 8; j++) l[j] = lows[rr * 8 + j];
        float* outp = out + (size_t)(rowbase + rr) * H_;
#pragma unroll
        for (int i16 = 0; i16 < 4; i16++) {
            int i = i16 * 64 + ig * 4;
            const float* wh = w_out_high + i * 8;
            float4 s;
            s.x = b_out_high[i + 0]; s.y = b_out_high[i + 1];
            s.z = b_out_high[i + 2]; s.w = b_out_high[i + 3];
#pragma unroll
            for (int j = 0; j < 8; j++) {
                s.x += l[j] * wh[j];
                s.y += l[j] * wh[8 + j];
                s.z += l[j] * wh[16 + j];
                s.w += l[j] * wh[24 + j];
            }
            *(float4*)(outp + i) = s;
        }
    }
}

extern "C" void kernel_launch(void* const* d_in, const int* in_sizes, int n_in,
                              void* d_out, int out_size, void* d_ws, size_t ws_size,
                              hipStream_t stream) {
    const float* x          = (const float*)d_in[0];
    const float* w_qkv_low  = (const float*)d_in[1];
    const float* b_qkv_low  = (const float*)d_in[2];
    const float* w_qkv_high = (const float*)d_in[3];
    const float* b_qkv_high = (const float*)d_in[4];
    const float* w_out_low  = (const float*)d_in[5];
    const float* b_out_low  = (const float*)d_in[6];
    const float* w_out_high = (const float*)d_in[7];
    const float* b_out_high = (const float*)d_in[8];
    // d_in[9] adj_u, d_in[10] adj_v: unused (attn_reg_loss is the constant REGW/N)
    float* ws = (float*)d_ws;
    float* out = (float*)d_out;

    ka_fused<<<512, 256, 0, stream>>>(x, w_qkv_low, b_qkv_low, w_qkv_high, b_qkv_high, ws);
    k2_kv<<<512, 256, 0, stream>>>(ws + KF_OFF, ws + V_OFF, ws + KVP_OFF);
    k2b_reduce<<<256, 256, 0, stream>>>(ws + KVP_OFF, ws + KVT_OFF, out);
    k4_out<<<512, 256, 0, stream>>>(ws, w_out_low, b_out_low, w_out_high, b_out_high, out);
}

// Round 4
// 143.898 us; speedup vs baseline: 1.1844x; 1.0757x over previous
//
#include <hip/hip_runtime.h>
#include <math.h>

// Problem constants
#define B_     4
#define N_     2048
#define H_     256
#define ROWS   8192    // B_*N_
#define EPS_   1e-8f
#define REGW   1e-5f
#define OUT_MAIN (ROWS*H_)   // 2097152

// Workspace layout (float offsets). Total ~42.3 MB.
#define QF_OFF  0
#define KF_OFF  (ROWS*H_)              // 2097152
#define V_OFF   (2*ROWS*H_)            // 4194304
#define Z_OFF   (3*ROWS*H_)            // 6291456  (ROWS*4, stores 1/(sum+eps))
#define KVP_OFF (Z_OFF + ROWS*4)       // 6324224  (1024*4096 partial kv)
#define KV_OFF  (KVP_OFF + 1024*4096)  // 10518528 (16*4096 kv, [bh][d*64+e])

static __device__ __forceinline__ float elu1(float x) {
    return x > 0.f ? x + 1.f : __expf(x);
}

// ---------------------------------------------------------------------------
// ka_fused: 512 blocks x 256 thr; block = 16 rows; thread = (r = t>>4, c4 = t&15).
// Phase b: lane's k-slice is INTERLEAVED (k = c4*4 + i*64) -> LDS reads are 16
// consecutive f4s per row-group (2-way, free). Width-16 butterfly leaves full
// qkv_low[24] in every lane's registers.
// Phase c: w_high chunk transposed in-block to k-major [24][260]; thread's 4
// output f4s are j = i*64 + c4*4 (i = 0..3); reads are 16-consecutive-f4
// (free) + broadcast across row groups; stores are coalesced f4.
// ---------------------------------------------------------------------------
__global__ __launch_bounds__(256) void ka_fused(
    const float* __restrict__ x, const float* __restrict__ w_low,
    const float* __restrict__ b_low, const float* __restrict__ w_high,
    const float* __restrict__ b_high, float* __restrict__ ws)
{
    __shared__ float bufA[24 * 260];  // w_low [j][k] stride 260; later chunk1^T
    __shared__ float bufB[24 * 260];  // w_high chunk0^T [k][j]; later chunk2^T

    const int t  = threadIdx.x;
    const int r  = t >> 4, c4 = t & 15;
    const size_t row = (size_t)blockIdx.x * 16 + r;

    // stage w_low [24][256] -> bufA[j*260+k] (straight copy; 2-way banks, free)
#pragma unroll
    for (int i = 0; i < 6; i++) {
        int g = t + i * 256;                 // f4 index
        int j = g >> 6, k = (g & 63) * 4;
        *(float4*)&bufA[j * 260 + k] = *(const float4*)(w_low + g * 4);
    }
    // stage + transpose w_high chunk0 [256][24] -> bufB[k*260 + j]
#pragma unroll
    for (int i = 0; i < 6; i++) {
        int g = t + i * 256;
        float4 v4 = *(const float4*)(w_high + g * 4);
        int e = g * 4, j = e / 24, k = e - j * 24;
        bufB[(k + 0) * 260 + j] = v4.x;
        bufB[(k + 1) * 260 + j] = v4.y;
        bufB[(k + 2) * 260 + j] = v4.z;
        bufB[(k + 3) * 260 + j] = v4.w;
    }
    // x slice into registers (coalesced 256B runs per (row,i))
    float4 xr[4];
#pragma unroll
    for (int i = 0; i < 4; i++)
        xr[i] = *(const float4*)(x + row * H_ + i * 64 + c4 * 4);
    __syncthreads();   // B1

    // phase b: partial over interleaved k-slice, butterfly width 16 -> ql[24]
    float ql[24];
#pragma unroll
    for (int j = 0; j < 24; j++) {
        float s = 0.f;
#pragma unroll
        for (int i = 0; i < 4; i++) {
            float4 w4 = *(const float4*)&bufA[j * 260 + i * 64 + c4 * 4];
            s += xr[i].x * w4.x + xr[i].y * w4.y + xr[i].z * w4.z + xr[i].w * w4.w;
        }
        s += __shfl_xor(s, 1, 16);
        s += __shfl_xor(s, 2, 16);
        s += __shfl_xor(s, 4, 16);
        s += __shfl_xor(s, 8, 16);
        ql[j] = s + b_low[j];
    }

    float* qf = ws + QF_OFF;
    float* kf = ws + KF_OFF;
    float* vv = ws + V_OFF;
    float* zg = ws + Z_OFF;

    // ---- chunk 0 (q): compute from bufB ----
    {
#pragma unroll
        for (int i = 0; i < 4; i++) {
            int jl = i * 64 + c4 * 4;
            float4 a = *(const float4*)(b_high + jl);
#pragma unroll
            for (int k = 0; k < 24; k++) {
                float4 w4 = *(const float4*)&bufB[k * 260 + jl];
                float q = ql[k];
                a.x += q * w4.x; a.y += q * w4.y; a.z += q * w4.z; a.w += q * w4.w;
            }
            a.x = elu1(a.x); a.y = elu1(a.y); a.z = elu1(a.z); a.w = elu1(a.w);
            *(float4*)(qf + row * H_ + jl) = a;
        }
    }
    __syncthreads();   // B2: everyone done with bufA (phase b)
    // stage + transpose chunk1 -> bufA
#pragma unroll
    for (int i = 0; i < 6; i++) {
        int g = t + i * 256;
        float4 v4 = *(const float4*)(w_high + 6144 + g * 4);
        int e = g * 4, j = e / 24, k = e - j * 24;
        bufA[(k + 0) * 260 + j] = v4.x;
        bufA[(k + 1) * 260 + j] = v4.y;
        bufA[(k + 2) * 260 + j] = v4.z;
        bufA[(k + 3) * 260 + j] = v4.w;
    }
    __syncthreads();   // B3

    // ---- chunk 1 (k + z): compute from bufA ----
    {
        float zp[4];
#pragma unroll
        for (int i = 0; i < 4; i++) {
            int jl = i * 64 + c4 * 4;
            float4 a = *(const float4*)(b_high + 256 + jl);
#pragma unroll
            for (int k = 0; k < 24; k++) {
                float4 w4 = *(const float4*)&bufA[k * 260 + jl];
                float q = ql[k];
                a.x += q * w4.x; a.y += q * w4.y; a.z += q * w4.z; a.w += q * w4.w;
            }
            a.x = elu1(a.x); a.y = elu1(a.y); a.z = elu1(a.z); a.w = elu1(a.w);
            *(float4*)(kf + row * H_ + jl) = a;
            zp[i] = a.x + a.y + a.z + a.w;
        }
#pragma unroll
        for (int i = 0; i < 4; i++) {
            float s = zp[i];
            s += __shfl_xor(s, 1, 16);
            s += __shfl_xor(s, 2, 16);
            s += __shfl_xor(s, 4, 16);
            s += __shfl_xor(s, 8, 16);
            zp[i] = s;
        }
        if (c4 == 0) {
            float4 zr;
            zr.x = 1.f / (zp[0] + EPS_);
            zr.y = 1.f / (zp[1] + EPS_);
            zr.z = 1.f / (zp[2] + EPS_);
            zr.w = 1.f / (zp[3] + EPS_);
            *(float4*)(zg + row * 4) = zr;
        }
    }
    __syncthreads();   // B4: everyone done with bufB (chunk0)
    // stage + transpose chunk2 -> bufB
#pragma unroll
    for (int i = 0; i < 6; i++) {
        int g = t + i * 256;
        float4 v4 = *(const float4*)(w_high + 12288 + g * 4);
        int e = g * 4, j = e / 24, k = e - j * 24;
        bufB[(k + 0) * 260 + j] = v4.x;
        bufB[(k + 1) * 260 + j] = v4.y;
        bufB[(k + 2) * 260 + j] = v4.z;
        bufB[(k + 3) * 260 + j] = v4.w;
    }
    __syncthreads();   // B5

    // ---- chunk 2 (v): compute from bufB ----
    {
#pragma unroll
        for (int i = 0; i < 4; i++) {
            int jl = i * 64 + c4 * 4;
            float4 a = *(const float4*)(b_high + 512 + jl);
#pragma unroll
            for (int k = 0; k < 24; k++) {
                float4 w4 = *(const float4*)&bufB[k * 260 + jl];
                float q = ql[k];
                a.x += q * w4.x; a.y += q * w4.y; a.z += q * w4.z; a.w += q * w4.w;
            }
            *(float4*)(vv + row * H_ + jl) = a;
        }
    }
}

// ---------------------------------------------------------------------------
// k2_kv: partial kv over 32-row chunks. Grid 1024 = b*256 + h*64 + ch.
// LDS-staged kf/v slices (stride 68, conflict-free), 4x4 register tile.
// 4 blocks/CU co-resident -> 16 waves/CU.
// ---------------------------------------------------------------------------
__global__ __launch_bounds__(256) void k2_kv(
    const float* __restrict__ kf, const float* __restrict__ v,
    float* __restrict__ kvp)
{
    __shared__ float kfs[32 * 68];
    __shared__ float vss[32 * 68];
    const int blk = blockIdx.x;
    const int b = blk >> 8, h = (blk >> 6) & 3, ch = blk & 63;
    const int t = threadIdx.x;
    const size_t base = ((size_t)b * N_ + ch * 32) * H_ + h * 64;
#pragma unroll
    for (int i = 0; i < 2; i++) {
        int g = t + i * 256;
        int r = g >> 4, c = (g & 15) * 4;
        *(float4*)&kfs[r * 68 + c] = *(const float4*)(kf + base + (size_t)r * H_ + c);
        *(float4*)&vss[r * 68 + c] = *(const float4*)(v  + base + (size_t)r * H_ + c);
    }
    __syncthreads();
    const int d0 = (t >> 4) * 4, e0 = (t & 15) * 4;
    float4 a0 = {0,0,0,0}, a1 = {0,0,0,0}, a2 = {0,0,0,0}, a3 = {0,0,0,0};
    for (int i = 0; i < 32; i++) {
        float4 kk = *(const float4*)&kfs[i * 68 + d0];  // 4 addrs, 16-lane bcast
        float4 vv4 = *(const float4*)&vss[i * 68 + e0]; // 16 consecutive f4s
        a0.x += kk.x * vv4.x; a0.y += kk.x * vv4.y; a0.z += kk.x * vv4.z; a0.w += kk.x * vv4.w;
        a1.x += kk.y * vv4.x; a1.y += kk.y * vv4.y; a1.z += kk.y * vv4.z; a1.w += kk.y * vv4.w;
        a2.x += kk.z * vv4.x; a2.y += kk.z * vv4.y; a2.z += kk.z * vv4.z; a2.w += kk.z * vv4.w;
        a3.x += kk.w * vv4.x; a3.y += kk.w * vv4.y; a3.z += kk.w * vv4.z; a3.w += kk.w * vv4.w;
    }
    float* outp = kvp + (size_t)blk * 4096;
    *(float4*)(outp + (d0 + 0) * 64 + e0) = a0;
    *(float4*)(outp + (d0 + 1) * 64 + e0) = a1;
    *(float4*)(outp + (d0 + 2) * 64 + e0) = a2;
    *(float4*)(outp + (d0 + 3) * 64 + e0) = a3;
}

// ---------------------------------------------------------------------------
// k2b: reduce 64 partials -> kv[bh][d*64+e] (natural layout; k4 wants [d][e]).
// Also writes the constant reg-loss (softmax rows sum to 1 => mean|attn|=1/N;
// adj_u/adj_v cannot change it). Grid 256 x 256.
// ---------------------------------------------------------------------------
__global__ __launch_bounds__(256) void k2b_reduce(
    const float* __restrict__ kvp, float* __restrict__ kvg,
    float* __restrict__ out)
{
    const int blk = blockIdx.x, t = threadIdx.x;
    const int bh = blk >> 4;
    const int idx = (blk & 15) * 256 + t;
    float s = 0.f;
#pragma unroll 8
    for (int c = 0; c < 64; c++)
        s += kvp[((size_t)bh * 64 + c) * 4096 + idx];
    kvg[(size_t)bh * 4096 + idx] = s;
    if (blk == 0 && t == 0)
        out[OUT_MAIN] = REGW / (float)N_;   // 4.8828125e-9
}

// ---------------------------------------------------------------------------
// k4_out: 512 blocks x 256 thr; block = 16 rows; thread = (r, c4).
// lin[r][i*64 + c4*4..+3] = z * sum_d qf[r][i*64+d] * kv[d][e]: qf staged in
// LDS (broadcast b128 reads, conflict-free), kv read from global (64 KB per
// batch, L2-hot, 256B coalesced runs). Then low/high projections, f4 stores.
// ---------------------------------------------------------------------------
__global__ __launch_bounds__(256) void k4_out(
    const float* __restrict__ ws,
    const float* __restrict__ w_out_low, const float* __restrict__ b_out_low,
    const float* __restrict__ w_out_high, const float* __restrict__ b_out_high,
    float* __restrict__ out)
{
    __shared__ float qfs[16 * 260];
    __shared__ float lin[16 * 260];
    __shared__ float lows[16 * 8];
    __shared__ float zs[64];

    const int t = threadIdx.x, blk = blockIdx.x;
    const int rowbase = blk * 16;
    const int b = blk >> 7;
    const float* qf  = ws + QF_OFF;
    const float* kvg = ws + KV_OFF + (size_t)b * 4 * 4096;

    // stage qf tile [16][256] -> stride 260 (2-way banks, free)
#pragma unroll
    for (int i = 0; i < 4; i++) {
        int g = t + i * 256;
        int r = g >> 6, c = (g & 63) * 4;
        *(float4*)&qfs[r * 260 + c] =
            *(const float4*)(qf + ((size_t)rowbase + r) * H_ + c);
    }
    if (t < 64) zs[t] = ws[Z_OFF + (size_t)rowbase * 4 + t];
    __syncthreads();

    const int r = t >> 4, c4 = t & 15;
#pragma unroll
    for (int i = 0; i < 4; i++) {
        float4 acc = {0.f, 0.f, 0.f, 0.f};
        const float* kvh = kvg + i * 4096 + c4 * 4;
        for (int d4 = 0; d4 < 16; d4++) {
            float4 qa = *(const float4*)&qfs[r * 260 + i * 64 + d4 * 4];
            float4 k0 = *(const float4*)(kvh + (d4 * 4 + 0) * 64);
            float4 k1 = *(const float4*)(kvh + (d4 * 4 + 1) * 64);
            float4 k2 = *(const float4*)(kvh + (d4 * 4 + 2) * 64);
            float4 k3 = *(const float4*)(kvh + (d4 * 4 + 3) * 64);
            acc.x += qa.x * k0.x + qa.y * k1.x + qa.z * k2.x + qa.w * k3.x;
            acc.y += qa.x * k0.y + qa.y * k1.y + qa.z * k2.y + qa.w * k3.y;
            acc.z += qa.x * k0.z + qa.y * k1.z + qa.z * k2.z + qa.w * k3.z;
            acc.w += qa.x * k0.w + qa.y * k1.w + qa.z * k2.w + qa.w * k3.w;
        }
        float zv = zs[r * 4 + i];
        *(float4*)&lin[r * 260 + i * 64 + c4 * 4] =
            make_float4(acc.x * zv, acc.y * zv, acc.z * zv, acc.w * zv);
    }
    __syncthreads();

    // low projection: 128 threads, (rr = t>>3, j = t&7); lin reads are 8
    // disjoint bank-quads x 8-lane broadcast (conflict-free).
    if (t < 128) {
        int rr = t >> 3, j = t & 7;
        float a = b_out_low[j];
        const float4* wj = (const float4*)(w_out_low + j * H_);
#pragma unroll
        for (int kq = 0; kq < 64; kq++) {
            float4 l4 = *(const float4*)&lin[rr * 260 + kq * 4];
            float4 w4 = wj[kq];
            a += l4.x * w4.x + l4.y * w4.y + l4.z * w4.z + l4.w * w4.w;
        }
        lows[rr * 8 + j] = a;
    }
    __syncthreads();

    // high projection: (rr = t>>4, ig = t&15); coalesced f4 stores.
    {
        int rr = t >> 4, ig = t & 15;
        float l[8];
#pragma unroll
        for (int j = 0; j < 8; j++) l[j] = lows[rr * 8 + j];
        float* outp = out + (size_t)(rowbase + rr) * H_;
#pragma unroll
        for (int i16 = 0; i16 < 4; i16++) {
            int i = i16 * 64 + ig * 4;
            const float* wh = w_out_high + i * 8;
            float4 s;
            s.x = b_out_high[i + 0]; s.y = b_out_high[i + 1];
            s.z = b_out_high[i + 2]; s.w = b_out_high[i + 3];
#pragma unroll
            for (int j = 0; j < 8; j++) {
                s.x += l[j] * wh[j];
                s.y += l[j] * wh[8 + j];
                s.z += l[j] * wh[16 + j];
                s.w += l[j] * wh[24 + j];
            }
            *(float4*)(outp + i) = s;
        }
    }
}

extern "C" void kernel_launch(void* const* d_in, const int* in_sizes, int n_in,
                              void* d_out, int out_size, void* d_ws, size_t ws_size,
                              hipStream_t stream) {
    const float* x          = (const float*)d_in[0];
    const float* w_qkv_low  = (const float*)d_in[1];
    const float* b_qkv_low  = (const float*)d_in[2];
    const float* w_qkv_high = (const float*)d_in[3];
    const float* b_qkv_high = (const float*)d_in[4];
    const float* w_out_low  = (const float*)d_in[5];
    const float* b_out_low  = (const float*)d_in[6];
    const float* w_out_high = (const float*)d_in[7];
    const float* b_out_high = (const float*)d_in[8];
    // d_in[9] adj_u, d_in[10] adj_v: unused (attn_reg_loss is the constant REGW/N)
    float* ws = (float*)d_ws;
    float* out = (float*)d_out;

    ka_fused<<<512, 256, 0, stream>>>(x, w_qkv_low, b_qkv_low, w_qkv_high, b_qkv_high, ws);
    k2_kv<<<1024, 256, 0, stream>>>(ws + KF_OFF, ws + V_OFF, ws + KVP_OFF);
    k2b_reduce<<<256, 256, 0, stream>>>(ws + KVP_OFF, ws + KV_OFF, out);
    k4_out<<<512, 256, 0, stream>>>(ws, w_out_low, b_out_low, w_out_high, b_out_high, out);
}

// Round 5
// 140.802 us; speedup vs baseline: 1.2104x; 1.0220x over previous
//
#include <hip/hip_runtime.h>
#include <math.h>

// Problem constants
#define B_     4
#define N_     2048
#define H_     256
#define ROWS   8192    // B_*N_
#define EPS_   1e-8f
#define REGW   1e-5f
#define OUT_MAIN (ROWS*H_)   // 2097152

static __device__ __forceinline__ float elu1(float x) {
    return x > 0.f ? x + 1.f : __expf(x);
}

// fp32 pair -> packed bf16x2 (RNE)
static __device__ __forceinline__ unsigned pack_bf16x2(float a, float b) {
    unsigned ua = __float_as_uint(a), ub = __float_as_uint(b);
    ua = (ua + 0x7FFFu + ((ua >> 16) & 1u)) >> 16;
    ub = (ub + 0x7FFFu + ((ub >> 16) & 1u)) & 0xFFFF0000u;
    return ua | ub;
}
// packed bf16x2 -> fp32 pair (exact: bf16 bits << 16)
static __device__ __forceinline__ float2 unpack_bf16x2(unsigned u) {
    return make_float2(__uint_as_float(u << 16), __uint_as_float(u & 0xFFFF0000u));
}

// ---------------------------------------------------------------------------
// ka_fused: 512 blocks x 256 thr; block = 16 rows.
// Phase b (thread = (row rb, kslice c4)): interleaved k-slices + width-16
// butterfly -> full qkv_low[24]; dropped into qlT[24][16] (LDS).
// Phase c (wave wv = 4 rows, lane c = j-f4): per k: 1 w-b128 (contiguous) +
// 1 qlT-b128 (64-lane broadcast) + 16 FMA. Outputs packed bf16, head-major
// [h][8192][64]. w_high chunks transposed to k-major [24][260] in LDS;
// transpose staging overlaps previous chunk's compute.
// ---------------------------------------------------------------------------
template<int MODE>  // 0 = q (elu), 1 = k (elu + z), 2 = v (raw)
static __device__ __forceinline__ void chunk_compute(
    const float* __restrict__ buf, const float* __restrict__ qlT,
    const float* __restrict__ b_high, int chunk, size_t rowbase,
    int wv, int c, unsigned* __restrict__ outu, float* __restrict__ zg)
{
    float4 bh4 = *(const float4*)(b_high + chunk * 256 + c * 4);
    float4 a0 = bh4, a1 = bh4, a2 = bh4, a3 = bh4;
#pragma unroll
    for (int k = 0; k < 24; k++) {
        float4 w4 = *(const float4*)&buf[k * 260 + c * 4];
        float4 q4 = *(const float4*)&qlT[k * 16 + wv * 4];   // broadcast
        a0.x += q4.x * w4.x; a0.y += q4.x * w4.y; a0.z += q4.x * w4.z; a0.w += q4.x * w4.w;
        a1.x += q4.y * w4.x; a1.y += q4.y * w4.y; a1.z += q4.y * w4.z; a1.w += q4.y * w4.w;
        a2.x += q4.z * w4.x; a2.y += q4.z * w4.y; a2.z += q4.z * w4.z; a2.w += q4.z * w4.w;
        a3.x += q4.w * w4.x; a3.y += q4.w * w4.y; a3.z += q4.w * w4.z; a3.w += q4.w * w4.w;
    }
    const int h = c >> 4, dq = (c & 15) * 2;   // uint offset in 32-uint row
    float4 aa[4] = {a0, a1, a2, a3};
    float zp[4];
#pragma unroll
    for (int rr = 0; rr < 4; rr++) {
        float4 a = aa[rr];
        if (MODE != 2) {
            a.x = elu1(a.x); a.y = elu1(a.y); a.z = elu1(a.z); a.w = elu1(a.w);
        }
        size_t row = rowbase + wv * 4 + rr;
        uint2 p;
        p.x = pack_bf16x2(a.x, a.y);
        p.y = pack_bf16x2(a.z, a.w);
        *(uint2*)(outu + ((size_t)h * ROWS + row) * 32 + dq) = p;
        if (MODE == 1) zp[rr] = a.x + a.y + a.z + a.w;
    }
    if (MODE == 1) {
#pragma unroll
        for (int rr = 0; rr < 4; rr++) {
            float s = zp[rr];
            s += __shfl_xor(s, 1, 16);
            s += __shfl_xor(s, 2, 16);
            s += __shfl_xor(s, 4, 16);
            s += __shfl_xor(s, 8, 16);
            zp[rr] = s;
        }
        if ((c & 15) == 0) {
#pragma unroll
            for (int rr = 0; rr < 4; rr++)
                zg[(rowbase + wv * 4 + rr) * 4 + h] = 1.f / (zp[rr] + EPS_);
        }
    }
}

static __device__ __forceinline__ void stage_whT(
    const float* __restrict__ wsrc, float* __restrict__ dst, int t)
{
#pragma unroll
    for (int i = 0; i < 6; i++) {
        int g = t + i * 256;
        float4 v4 = *(const float4*)(wsrc + g * 4);
        int e = g * 4, j = e / 24, k = e - j * 24;
        dst[(k + 0) * 260 + j] = v4.x;
        dst[(k + 1) * 260 + j] = v4.y;
        dst[(k + 2) * 260 + j] = v4.z;
        dst[(k + 3) * 260 + j] = v4.w;
    }
}

__global__ __launch_bounds__(256) void ka_fused(
    const float* __restrict__ x, const float* __restrict__ w_low,
    const float* __restrict__ b_low, const float* __restrict__ w_high,
    const float* __restrict__ b_high,
    unsigned* __restrict__ qf_u, unsigned* __restrict__ kf_u,
    unsigned* __restrict__ v_u, float* __restrict__ zg)
{
    __shared__ float bufA[24 * 260];
    __shared__ float bufB[24 * 260];
    __shared__ float qlT[24 * 16];

    const int t = threadIdx.x;
    const size_t rowbase = (size_t)blockIdx.x * 16;
    const int rb = t >> 4, c4 = t & 15;   // phase-b ids
    const int wv = t >> 6, c  = t & 63;   // phase-c ids

    // stage w_low [24][256] -> bufA[j*260+k] (straight copy)
#pragma unroll
    for (int i = 0; i < 6; i++) {
        int g = t + i * 256;
        int j = g >> 6, k = (g & 63) * 4;
        *(float4*)&bufA[j * 260 + k] = *(const float4*)(w_low + g * 4);
    }
    // stage + transpose w_high chunk0 -> bufB[k][j]
    stage_whT(w_high, bufB, t);
    // x slice into registers (interleaved k-slices, coalesced)
    float4 xr[4];
#pragma unroll
    for (int i = 0; i < 4; i++)
        xr[i] = *(const float4*)(x + (rowbase + rb) * H_ + i * 64 + c4 * 4);
    __syncthreads();   // B1

    // phase b: partial dot over lane's k-slice, butterfly width 16
    {
        float ql[24];
#pragma unroll
        for (int j = 0; j < 24; j++) {
            float s = 0.f;
#pragma unroll
            for (int i = 0; i < 4; i++) {
                float4 w4 = *(const float4*)&bufA[j * 260 + i * 64 + c4 * 4];
                s += xr[i].x * w4.x + xr[i].y * w4.y + xr[i].z * w4.z + xr[i].w * w4.w;
            }
            s += __shfl_xor(s, 1, 16);
            s += __shfl_xor(s, 2, 16);
            s += __shfl_xor(s, 4, 16);
            s += __shfl_xor(s, 8, 16);
            ql[j] = s + b_low[j];
        }
        qlT[c4 * 16 + rb] = ql[c4];
        if (c4 < 8) qlT[(16 + c4) * 16 + rb] = ql[16 + c4];
    }
    __syncthreads();   // B2: qlT visible; bufA free

    chunk_compute<0>(bufB, qlT, b_high, 0, rowbase, wv, c, qf_u, zg);
    stage_whT(w_high + 6144, bufA, t);      // chunk1^T -> bufA
    __syncthreads();   // B3

    chunk_compute<1>(bufA, qlT, b_high, 1, rowbase, wv, c, kf_u, zg);
    stage_whT(w_high + 12288, bufB, t);     // chunk2^T -> bufB (chunk0 done)
    __syncthreads();   // B4

    chunk_compute<2>(bufB, qlT, b_high, 2, rowbase, wv, c, v_u, zg);
}

// ---------------------------------------------------------------------------
// k2_kv: partial kv over 64-row chunks. Grid 512 = b*128 + h*32 + ch.
// Head-major bf16 input -> fully contiguous 8 KB reads per array; unpack once
// into fp32 LDS (stride 68, conflict-free); 4x4 register tile.
// ---------------------------------------------------------------------------
__global__ __launch_bounds__(256) void k2_kv(
    const unsigned* __restrict__ kfu, const unsigned* __restrict__ vu,
    float* __restrict__ kvp)
{
    __shared__ float kfs[64 * 68];
    __shared__ float vss[64 * 68];
    const int blk = blockIdx.x;
    const int b = blk >> 7, h = (blk >> 5) & 3, ch = blk & 31;
    const int t = threadIdx.x;
    const size_t base_u = ((size_t)h * ROWS + (size_t)b * N_ + ch * 64) * 32;
#pragma unroll
    for (int i = 0; i < 2; i++) {
        int g = t + i * 256;
        int r = g >> 3, q = g & 7;
        uint4 ku = *(const uint4*)(kfu + base_u + r * 32 + q * 4);
        uint4 vv4 = *(const uint4*)(vu + base_u + r * 32 + q * 4);
        float2 f0 = unpack_bf16x2(ku.x), f1 = unpack_bf16x2(ku.y);
        float2 f2 = unpack_bf16x2(ku.z), f3 = unpack_bf16x2(ku.w);
        *(float4*)&kfs[r * 68 + q * 8 + 0] = make_float4(f0.x, f0.y, f1.x, f1.y);
        *(float4*)&kfs[r * 68 + q * 8 + 4] = make_float4(f2.x, f2.y, f3.x, f3.y);
        f0 = unpack_bf16x2(vv4.x); f1 = unpack_bf16x2(vv4.y);
        f2 = unpack_bf16x2(vv4.z); f3 = unpack_bf16x2(vv4.w);
        *(float4*)&vss[r * 68 + q * 8 + 0] = make_float4(f0.x, f0.y, f1.x, f1.y);
        *(float4*)&vss[r * 68 + q * 8 + 4] = make_float4(f2.x, f2.y, f3.x, f3.y);
    }
    __syncthreads();
    const int d0 = (t >> 4) * 4, e0 = (t & 15) * 4;
    float4 a0 = {0,0,0,0}, a1 = {0,0,0,0}, a2 = {0,0,0,0}, a3 = {0,0,0,0};
    for (int i = 0; i < 64; i++) {
        float4 kk = *(const float4*)&kfs[i * 68 + d0];
        float4 v4 = *(const float4*)&vss[i * 68 + e0];
        a0.x += kk.x * v4.x; a0.y += kk.x * v4.y; a0.z += kk.x * v4.z; a0.w += kk.x * v4.w;
        a1.x += kk.y * v4.x; a1.y += kk.y * v4.y; a1.z += kk.y * v4.z; a1.w += kk.y * v4.w;
        a2.x += kk.z * v4.x; a2.y += kk.z * v4.y; a2.z += kk.z * v4.z; a2.w += kk.z * v4.w;
        a3.x += kk.w * v4.x; a3.y += kk.w * v4.y; a3.z += kk.w * v4.z; a3.w += kk.w * v4.w;
    }
    float* outp = kvp + (size_t)blk * 4096;
    *(float4*)(outp + (d0 + 0) * 64 + e0) = a0;
    *(float4*)(outp + (d0 + 1) * 64 + e0) = a1;
    *(float4*)(outp + (d0 + 2) * 64 + e0) = a2;
    *(float4*)(outp + (d0 + 3) * 64 + e0) = a3;
}

// ---------------------------------------------------------------------------
// k2b: reduce 32 partials -> kv[bh][d*64+e]; write constant reg-loss
// (softmax rows sum to 1 => mean|attn| == 1/N; adj_u/adj_v cannot change it).
// Grid 256 x 256.
// ---------------------------------------------------------------------------
__global__ __launch_bounds__(256) void k2b_reduce(
    const float* __restrict__ kvp, float* __restrict__ kvg,
    float* __restrict__ out)
{
    const int blk = blockIdx.x, t = threadIdx.x;
    const int bh = blk >> 4;
    const size_t pbase = (size_t)((bh >> 2) * 128 + (bh & 3) * 32);
    const int idx = (blk & 15) * 256 + t;
    float s = 0.f;
#pragma unroll 8
    for (int c = 0; c < 32; c++)
        s += kvp[(pbase + c) * 4096 + idx];
    kvg[(size_t)bh * 4096 + idx] = s;
    if (blk == 0 && t == 0)
        out[OUT_MAIN] = REGW / (float)N_;   // 4.8828125e-9
}

// ---------------------------------------------------------------------------
// k4_out: 512 blocks x 256 thr; block = 16 rows. bf16 head-major qf unpacked
// into fp32 LDS tile [16][260]; kv read from global (L2-hot, coalesced);
// then low/high projections, f4 stores.
// ---------------------------------------------------------------------------
__global__ __launch_bounds__(256) void k4_out(
    const unsigned* __restrict__ qfu, const float* __restrict__ zg,
    const float* __restrict__ kvg,
    const float* __restrict__ w_out_low, const float* __restrict__ b_out_low,
    const float* __restrict__ w_out_high, const float* __restrict__ b_out_high,
    float* __restrict__ out)
{
    __shared__ float qfs[16 * 260];
    __shared__ float lin[16 * 260];
    __shared__ float lows[16 * 8];
    __shared__ float zs[64];

    const int t = threadIdx.x, blk = blockIdx.x;
    const int rowbase = blk * 16;
    const int b = blk >> 7;
    const float* kvb = kvg + (size_t)b * 4 * 4096;

    // stage qf tile: head-major bf16 -> fp32 [r][h*64+d], stride 260
#pragma unroll
    for (int i = 0; i < 2; i++) {
        int g = t + i * 256;
        int h = g >> 7, rr = (g >> 3) & 15, q = g & 7;
        uint4 u = *(const uint4*)(qfu + ((size_t)h * ROWS + rowbase + rr) * 32 + q * 4);
        float2 f0 = unpack_bf16x2(u.x), f1 = unpack_bf16x2(u.y);
        float2 f2 = unpack_bf16x2(u.z), f3 = unpack_bf16x2(u.w);
        *(float4*)&qfs[rr * 260 + h * 64 + q * 8 + 0] = make_float4(f0.x, f0.y, f1.x, f1.y);
        *(float4*)&qfs[rr * 260 + h * 64 + q * 8 + 4] = make_float4(f2.x, f2.y, f3.x, f3.y);
    }
    if (t < 64) zs[t] = zg[(size_t)rowbase * 4 + t];
    __syncthreads();

    const int r = t >> 4, c4 = t & 15;
#pragma unroll
    for (int i = 0; i < 4; i++) {
        float4 acc = {0.f, 0.f, 0.f, 0.f};
        const float* kvh = kvb + i * 4096 + c4 * 4;
        for (int d4 = 0; d4 < 16; d4++) {
            float4 qa = *(const float4*)&qfs[r * 260 + i * 64 + d4 * 4];
            float4 k0 = *(const float4*)(kvh + (d4 * 4 + 0) * 64);
            float4 k1 = *(const float4*)(kvh + (d4 * 4 + 1) * 64);
            float4 k2 = *(const float4*)(kvh + (d4 * 4 + 2) * 64);
            float4 k3 = *(const float4*)(kvh + (d4 * 4 + 3) * 64);
            acc.x += qa.x * k0.x + qa.y * k1.x + qa.z * k2.x + qa.w * k3.x;
            acc.y += qa.x * k0.y + qa.y * k1.y + qa.z * k2.y + qa.w * k3.y;
            acc.z += qa.x * k0.z + qa.y * k1.z + qa.z * k2.z + qa.w * k3.z;
            acc.w += qa.x * k0.w + qa.y * k1.w + qa.z * k2.w + qa.w * k3.w;
        }
        float zv = zs[r * 4 + i];
        *(float4*)&lin[r * 260 + i * 64 + c4 * 4] =
            make_float4(acc.x * zv, acc.y * zv, acc.z * zv, acc.w * zv);
    }
    __syncthreads();

    if (t < 128) {
        int rr = t >> 3, j = t & 7;
        float a = b_out_low[j];
        const float4* wj = (const float4*)(w_out_low + j * H_);
#pragma unroll
        for (int kq = 0; kq < 64; kq++) {
            float4 l4 = *(const float4*)&lin[rr * 260 + kq * 4];
            float4 w4 = wj[kq];
            a += l4.x * w4.x + l4.y * w4.y + l4.z * w4.z + l4.w * w4.w;
        }
        lows[rr * 8 + j] = a;
    }
    __syncthreads();

    {
        int rr = t >> 4, ig = t & 15;
        float l[8];
#pragma unroll
        for (int j = 0; j < 8; j++) l[j] = lows[rr * 8 + j];
        float* outp = out + (size_t)(rowbase + rr) * H_;
#pragma unroll
        for (int i16 = 0; i16 < 4; i16++) {
            int i = i16 * 64 + ig * 4;
            const float* wh = w_out_high + i * 8;
            float4 s;
            s.x = b_out_high[i + 0]; s.y = b_out_high[i + 1];
            s.z = b_out_high[i + 2]; s.w = b_out_high[i + 3];
#pragma unroll
            for (int j = 0; j < 8; j++) {
                s.x += l[j] * wh[j];
                s.y += l[j] * wh[8 + j];
                s.z += l[j] * wh[16 + j];
                s.w += l[j] * wh[24 + j];
            }
            *(float4*)(outp + i) = s;
        }
    }
}

extern "C" void kernel_launch(void* const* d_in, const int* in_sizes, int n_in,
                              void* d_out, int out_size, void* d_ws, size_t ws_size,
                              hipStream_t stream) {
    const float* x          = (const float*)d_in[0];
    const float* w_qkv_low  = (const float*)d_in[1];
    const float* b_qkv_low  = (const float*)d_in[2];
    const float* w_qkv_high = (const float*)d_in[3];
    const float* b_qkv_high = (const float*)d_in[4];
    const float* w_out_low  = (const float*)d_in[5];
    const float* b_out_low  = (const float*)d_in[6];
    const float* w_out_high = (const float*)d_in[7];
    const float* b_out_high = (const float*)d_in[8];
    // d_in[9] adj_u, d_in[10] adj_v: unused (attn_reg_loss is the constant REGW/N)
    char* wsb = (char*)d_ws;
    unsigned* qf_u = (unsigned*)(wsb);                        // 4 MB  bf16 [4][8192][64]
    unsigned* kf_u = (unsigned*)(wsb + ((size_t)4 << 20));    // 4 MB
    unsigned* v_u  = (unsigned*)(wsb + ((size_t)8 << 20));    // 4 MB
    float*    zg   = (float*)(wsb + ((size_t)12 << 20));      // 128 KB fp32 [8192][4]
    float*    kvp  = (float*)(wsb + ((size_t)13 << 20));      // 8 MB  fp32 [512][4096]
    float*    kvg  = (float*)(wsb + ((size_t)21 << 20));      // 256 KB fp32 [16][4096]
    float* out = (float*)d_out;

    ka_fused<<<512, 256, 0, stream>>>(x, w_qkv_low, b_qkv_low, w_qkv_high,
                                      b_qkv_high, qf_u, kf_u, v_u, zg);
    k2_kv<<<512, 256, 0, stream>>>(kf_u, v_u, kvp);
    k2b_reduce<<<256, 256, 0, stream>>>(kvp, kvg, out);
    k4_out<<<512, 256, 0, stream>>>(qf_u, zg, kvg, w_out_low, b_out_low,
                                    w_out_high, b_out_high, out);
}

// Round 7
// 136.863 us; speedup vs baseline: 1.2452x; 1.0288x over previous
//
#include <hip/hip_runtime.h>
#include <math.h>

// Problem constants
#define B_     4
#define N_     2048
#define H_     256
#define ROWS   8192    // B_*N_
#define EPS_   1e-8f
#define REGW   1e-5f
#define OUT_MAIN (ROWS*H_)   // 2097152

static __device__ __forceinline__ float elu1(float x) {
    return x > 0.f ? x + 1.f : __expf(x);
}

// fp32 pair -> packed bf16x2 (RNE)
static __device__ __forceinline__ unsigned pack_bf16x2(float a, float b) {
    unsigned ua = __float_as_uint(a), ub = __float_as_uint(b);
    ua = (ua + 0x7FFFu + ((ua >> 16) & 1u)) >> 16;
    ub = (ub + 0x7FFFu + ((ub >> 16) & 1u)) & 0xFFFF0000u;
    return ua | ub;
}
// packed bf16x2 -> fp32 pair (exact)
static __device__ __forceinline__ float2 unpack_bf16x2(unsigned u) {
    return make_float2(__uint_as_float(u << 16), __uint_as_float(u & 0xFFFF0000u));
}

// stage + transpose a 256-row w_high chunk [256][24] -> dst[k*260 + j]
static __device__ __forceinline__ void stage_whT(
    const float* __restrict__ wsrc, float* __restrict__ dst, int t)
{
#pragma unroll
    for (int i = 0; i < 6; i++) {
        int g = t + i * 256;
        float4 v4 = *(const float4*)(wsrc + g * 4);
        int e = g * 4, j = e / 24, k = e - j * 24;
        dst[(k + 0) * 260 + j] = v4.x;
        dst[(k + 1) * 260 + j] = v4.y;
        dst[(k + 2) * 260 + j] = v4.z;
        dst[(k + 3) * 260 + j] = v4.w;
    }
}

// ---------------------------------------------------------------------------
// ka_fused: 512 blocks x 256 thr; block = 16 rows.
// Phase b: interleaved k-slices + width-16 butterfly -> full qkv_low[24] in
// regs; written to global ql (col-major [24][8192], 786 KB) and qlT LDS.
// Phase c: only k and v chunks (q is recomputed in k4 from ql). Per k-step:
// 1 w-b128 (16 consecutive f4s, free) + 1 qlT-b128 (broadcast) + 16 FMA.
// Outputs packed bf16 head-major [h][8192][64]; z = 1/(rowsum kf + eps).
// ---------------------------------------------------------------------------
template<int MODE>  // 1 = k (elu + z), 2 = v (raw)
static __device__ __forceinline__ void chunk_compute(
    const float* __restrict__ buf, const float* __restrict__ qlT,
    const float* __restrict__ b_high, size_t rowbase,
    int wv, int c, unsigned* __restrict__ outu, float* __restrict__ zg)
{
    const int chunk = (MODE == 1) ? 1 : 2;
    float4 bh4 = *(const float4*)(b_high + chunk * 256 + c * 4);
    float4 a0 = bh4, a1 = bh4, a2 = bh4, a3 = bh4;
#pragma unroll
    for (int k = 0; k < 24; k++) {
        float4 w4 = *(const float4*)&buf[k * 260 + c * 4];
        float4 q4 = *(const float4*)&qlT[k * 16 + wv * 4];   // broadcast
        a0.x += q4.x * w4.x; a0.y += q4.x * w4.y; a0.z += q4.x * w4.z; a0.w += q4.x * w4.w;
        a1.x += q4.y * w4.x; a1.y += q4.y * w4.y; a1.z += q4.y * w4.z; a1.w += q4.y * w4.w;
        a2.x += q4.z * w4.x; a2.y += q4.z * w4.y; a2.z += q4.z * w4.z; a2.w += q4.z * w4.w;
        a3.x += q4.w * w4.x; a3.y += q4.w * w4.y; a3.z += q4.w * w4.z; a3.w += q4.w * w4.w;
    }
    const int h = c >> 4, dq = (c & 15) * 2;
    float4 aa[4] = {a0, a1, a2, a3};
    float zp[4];
#pragma unroll
    for (int rr = 0; rr < 4; rr++) {
        float4 a = aa[rr];
        if (MODE == 1) {
            a.x = elu1(a.x); a.y = elu1(a.y); a.z = elu1(a.z); a.w = elu1(a.w);
        }
        size_t row = rowbase + wv * 4 + rr;
        uint2 p;
        p.x = pack_bf16x2(a.x, a.y);
        p.y = pack_bf16x2(a.z, a.w);
        *(uint2*)(outu + ((size_t)h * ROWS + row) * 32 + dq) = p;
        if (MODE == 1) zp[rr] = a.x + a.y + a.z + a.w;
    }
    if (MODE == 1) {
#pragma unroll
        for (int rr = 0; rr < 4; rr++) {
            float s = zp[rr];
            s += __shfl_xor(s, 1, 16);
            s += __shfl_xor(s, 2, 16);
            s += __shfl_xor(s, 4, 16);
            s += __shfl_xor(s, 8, 16);
            zp[rr] = s;
        }
        if ((c & 15) == 0) {
#pragma unroll
            for (int rr = 0; rr < 4; rr++)
                zg[(rowbase + wv * 4 + rr) * 4 + h] = 1.f / (zp[rr] + EPS_);
        }
    }
}

__global__ __launch_bounds__(256) void ka_fused(
    const float* __restrict__ x, const float* __restrict__ w_low,
    const float* __restrict__ b_low, const float* __restrict__ w_high,
    const float* __restrict__ b_high, float* __restrict__ g_ql,
    unsigned* __restrict__ kf_u, unsigned* __restrict__ v_u,
    float* __restrict__ zg)
{
    __shared__ float bufA[24 * 260];
    __shared__ float bufB[24 * 260];
    __shared__ float qlT[24 * 16];

    const int t = threadIdx.x;
    const size_t rowbase = (size_t)blockIdx.x * 16;
    const int rb = t >> 4, c4 = t & 15;   // phase-b ids
    const int wv = t >> 6, c  = t & 63;   // phase-c ids

    // stage w_low [24][256] -> bufA[j*260+k] (straight copy)
#pragma unroll
    for (int i = 0; i < 6; i++) {
        int g = t + i * 256;
        int j = g >> 6, k = (g & 63) * 4;
        *(float4*)&bufA[j * 260 + k] = *(const float4*)(w_low + g * 4);
    }
    // stage + transpose w_high chunk1 (k-weights) -> bufB
    stage_whT(w_high + 6144, bufB, t);
    // x slice into registers (interleaved k-slices, coalesced)
    float4 xr[4];
#pragma unroll
    for (int i = 0; i < 4; i++)
        xr[i] = *(const float4*)(x + (rowbase + rb) * H_ + i * 64 + c4 * 4);
    __syncthreads();   // B1

    // phase b -> ql[24] (all lanes of a row-group hold the full vector)
    {
        float ql[24];
#pragma unroll
        for (int j = 0; j < 24; j++) {
            float s = 0.f;
#pragma unroll
            for (int i = 0; i < 4; i++) {
                float4 w4 = *(const float4*)&bufA[j * 260 + i * 64 + c4 * 4];
                s += xr[i].x * w4.x + xr[i].y * w4.y + xr[i].z * w4.z + xr[i].w * w4.w;
            }
            s += __shfl_xor(s, 1, 16);
            s += __shfl_xor(s, 2, 16);
            s += __shfl_xor(s, 4, 16);
            s += __shfl_xor(s, 8, 16);
            ql[j] = s + b_low[j];
        }
        // global ql col-major [k][row]: 64B runs per (k, rowgroup)
        size_t row = rowbase + rb;
        g_ql[(size_t)c4 * ROWS + row] = ql[c4];
        if (c4 < 8) g_ql[(size_t)(16 + c4) * ROWS + row] = ql[16 + c4];
        qlT[c4 * 16 + rb] = ql[c4];
        if (c4 < 8) qlT[(16 + c4) * 16 + rb] = ql[16 + c4];
    }
    __syncthreads();   // B2: qlT visible; bufA free

    stage_whT(w_high + 12288, bufA, t);     // v-weights -> bufA (overlaps kf)
    chunk_compute<1>(bufB, qlT, b_high, rowbase, wv, c, kf_u, zg);
    __syncthreads();   // B3

    chunk_compute<2>(bufA, qlT, b_high, rowbase, wv, c, v_u, zg);
}

// ---------------------------------------------------------------------------
// k2_kv: partial kv over 128-row chunks. Grid 256 = b*64 + h*16 + ch.
// Head-major bf16 input -> contiguous 16 KB reads per array; unpack once into
// fp32 LDS (stride 68, conflict-free); 4x4 register tile, 128-deep.
// ---------------------------------------------------------------------------
__global__ __launch_bounds__(256) void k2_kv(
    const unsigned* __restrict__ kfu, const unsigned* __restrict__ vu,
    float* __restrict__ kvp)
{
    __shared__ float kfs[128 * 68];
    __shared__ float vss[128 * 68];
    const int blk = blockIdx.x;
    const int b = blk >> 6, h = (blk >> 4) & 3, ch = blk & 15;
    const int t = threadIdx.x;
    const size_t base_u = ((size_t)h * ROWS + (size_t)b * N_ + ch * 128) * 32;
#pragma unroll
    for (int i = 0; i < 4; i++) {
        int g = t + i * 256;
        int r = g >> 3, q = g & 7;
        uint4 ku = *(const uint4*)(kfu + base_u + r * 32 + q * 4);
        uint4 vv4 = *(const uint4*)(vu + base_u + r * 32 + q * 4);
        float2 f0 = unpack_bf16x2(ku.x), f1 = unpack_bf16x2(ku.y);
        float2 f2 = unpack_bf16x2(ku.z), f3 = unpack_bf16x2(ku.w);
        *(float4*)&kfs[r * 68 + q * 8 + 0] = make_float4(f0.x, f0.y, f1.x, f1.y);
        *(float4*)&kfs[r * 68 + q * 8 + 4] = make_float4(f2.x, f2.y, f3.x, f3.y);
        f0 = unpack_bf16x2(vv4.x); f1 = unpack_bf16x2(vv4.y);
        f2 = unpack_bf16x2(vv4.z); f3 = unpack_bf16x2(vv4.w);
        *(float4*)&vss[r * 68 + q * 8 + 0] = make_float4(f0.x, f0.y, f1.x, f1.y);
        *(float4*)&vss[r * 68 + q * 8 + 4] = make_float4(f2.x, f2.y, f3.x, f3.y);
    }
    __syncthreads();
    const int d0 = (t >> 4) * 4, e0 = (t & 15) * 4;
    float4 a0 = {0,0,0,0}, a1 = {0,0,0,0}, a2 = {0,0,0,0}, a3 = {0,0,0,0};
    for (int i = 0; i < 128; i++) {
        float4 kk = *(const float4*)&kfs[i * 68 + d0];
        float4 v4 = *(const float4*)&vss[i * 68 + e0];
        a0.x += kk.x * v4.x; a0.y += kk.x * v4.y; a0.z += kk.x * v4.z; a0.w += kk.x * v4.w;
        a1.x += kk.y * v4.x; a1.y += kk.y * v4.y; a1.z += kk.y * v4.z; a1.w += kk.y * v4.w;
        a2.x += kk.z * v4.x; a2.y += kk.z * v4.y; a2.z += kk.z * v4.z; a2.w += kk.z * v4.w;
        a3.x += kk.w * v4.x; a3.y += kk.w * v4.y; a3.z += kk.w * v4.z; a3.w += kk.w * v4.w;
    }
    float* outp = kvp + (size_t)blk * 4096;
    *(float4*)(outp + (d0 + 0) * 64 + e0) = a0;
    *(float4*)(outp + (d0 + 1) * 64 + e0) = a1;
    *(float4*)(outp + (d0 + 2) * 64 + e0) = a2;
    *(float4*)(outp + (d0 + 3) * 64 + e0) = a3;
}

// ---------------------------------------------------------------------------
// k2b: reduce 16 partials -> kv[bh][d*64+e]; write constant reg-loss
// (softmax rows sum to 1 => mean|attn| == 1/N; adj_u/adj_v cannot change it).
// Grid 256 x 256.
// ---------------------------------------------------------------------------
__global__ __launch_bounds__(256) void k2b_reduce(
    const float* __restrict__ kvp, float* __restrict__ kvg,
    float* __restrict__ out)
{
    const int blk = blockIdx.x, t = threadIdx.x;
    const int bh = blk >> 4;
    const size_t pbase = (size_t)((bh >> 2) * 64 + (bh & 3) * 16);
    const int idx = (blk & 15) * 256 + t;
    float s = 0.f;
#pragma unroll
    for (int c = 0; c < 16; c++)
        s += kvp[(pbase + c) * 4096 + idx];
    kvg[(size_t)bh * 4096 + idx] = s;
    if (blk == 0 && t == 0)
        out[OUT_MAIN] = REGW / (float)N_;   // 4.8828125e-9
}

// ---------------------------------------------------------------------------
// k4_out: 512 blocks x 256 thr; block = 16 rows. Recomputes qf = elu(ql @
// w_high_q^T) from the 1.5 KB ql tile (fp32 — never bf16-rounded) into LDS;
// lin = z * qf @ kv (kv from global, L2-hot); then low/high projections.
// ---------------------------------------------------------------------------
__global__ __launch_bounds__(256) void k4_out(
    const float* __restrict__ g_ql, const float* __restrict__ w_high,
    const float* __restrict__ b_high, const float* __restrict__ zg,
    const float* __restrict__ kvg,
    const float* __restrict__ w_out_low, const float* __restrict__ b_out_low,
    const float* __restrict__ w_out_high, const float* __restrict__ b_out_high,
    float* __restrict__ out)
{
    __shared__ float bufW[24 * 260];   // w_high q-chunk^T [k][j]
    __shared__ float qfs[16 * 260];
    __shared__ float lin[16 * 260];
    __shared__ float qlT[24 * 16];
    __shared__ float lows[16 * 8];
    __shared__ float zs[64];

    const int t = threadIdx.x, blk = blockIdx.x;
    const int rowbase = blk * 16;
    const int b = blk >> 7;
    const float* kvb = kvg + (size_t)b * 4 * 4096;

    stage_whT(w_high, bufW, t);            // q-weights
    // stage qlT: 384 entries with 256 threads (each loads 1; t<128 loads 2)
    {
        int k = t >> 4, r = t & 15;
        qlT[t] = g_ql[(size_t)k * ROWS + rowbase + r];
        if (t < 128) {
            int idx2 = 256 + t;
            int k2 = idx2 >> 4, r2 = idx2 & 15;
            qlT[idx2] = g_ql[(size_t)k2 * ROWS + rowbase + r2];
        }
    }
    if (t < 64) zs[t] = zg[(size_t)rowbase * 4 + t];
    __syncthreads();

    // recompute qf for 4 rows x 1 j-f4 per lane -> qfs
    {
        const int wv = t >> 6, c = t & 63;
        float4 bh4 = *(const float4*)(b_high + c * 4);
        float4 a0 = bh4, a1 = bh4, a2 = bh4, a3 = bh4;
#pragma unroll
        for (int k = 0; k < 24; k++) {
            float4 w4 = *(const float4*)&bufW[k * 260 + c * 4];
            float4 q4 = *(const float4*)&qlT[k * 16 + wv * 4];
            a0.x += q4.x * w4.x; a0.y += q4.x * w4.y; a0.z += q4.x * w4.z; a0.w += q4.x * w4.w;
            a1.x += q4.y * w4.x; a1.y += q4.y * w4.y; a1.z += q4.y * w4.z; a1.w += q4.y * w4.w;
            a2.x += q4.z * w4.x; a2.y += q4.z * w4.y; a2.z += q4.z * w4.z; a2.w += q4.z * w4.w;
            a3.x += q4.w * w4.x; a3.y += q4.w * w4.y; a3.z += q4.w * w4.z; a3.w += q4.w * w4.w;
        }
        float4 aa[4] = {a0, a1, a2, a3};
#pragma unroll
        for (int rr = 0; rr < 4; rr++) {
            float4 a = aa[rr];
            a.x = elu1(a.x); a.y = elu1(a.y); a.z = elu1(a.z); a.w = elu1(a.w);
            *(float4*)&qfs[(wv * 4 + rr) * 260 + c * 4] = a;
        }
    }
    __syncthreads();

    const int r = t >> 4, c4 = t & 15;
#pragma unroll
    for (int i = 0; i < 4; i++) {
        float4 acc = {0.f, 0.f, 0.f, 0.f};
        const float* kvh = kvb + i * 4096 + c4 * 4;
        for (int d4 = 0; d4 < 16; d4++) {
            float4 qa = *(const float4*)&qfs[r * 260 + i * 64 + d4 * 4];
            float4 k0 = *(const float4*)(kvh + (d4 * 4 + 0) * 64);
            float4 k1 = *(const float4*)(kvh + (d4 * 4 + 1) * 64);
            float4 k2 = *(const float4*)(kvh + (d4 * 4 + 2) * 64);
            float4 k3 = *(const float4*)(kvh + (d4 * 4 + 3) * 64);
            acc.x += qa.x * k0.x + qa.y * k1.x + qa.z * k2.x + qa.w * k3.x;
            acc.y += qa.x * k0.y + qa.y * k1.y + qa.z * k2.y + qa.w * k3.y;
            acc.z += qa.x * k0.z + qa.y * k1.z + qa.z * k2.z + qa.w * k3.z;
            acc.w += qa.x * k0.w + qa.y * k1.w + qa.z * k2.w + qa.w * k3.w;
        }
        float zv = zs[r * 4 + i];
        *(float4*)&lin[r * 260 + i * 64 + c4 * 4] =
            make_float4(acc.x * zv, acc.y * zv, acc.z * zv, acc.w * zv);
    }
    __syncthreads();

    if (t < 128) {
        int rr = t >> 3, j = t & 7;
        float a = b_out_low[j];
        const float4* wj = (const float4*)(w_out_low + j * H_);
#pragma unroll
        for (int kq = 0; kq < 64; kq++) {
            float4 l4 = *(const float4*)&lin[rr * 260 + kq * 4];
            float4 w4 = wj[kq];
            a += l4.x * w4.x + l4.y * w4.y + l4.z * w4.z + l4.w * w4.w;
        }
        lows[rr * 8 + j] = a;
    }
    __syncthreads();

    {
        int rr = t >> 4, ig = t & 15;
        float l[8];
#pragma unroll
        for (int j = 0; j < 8; j++) l[j] = lows[rr * 8 + j];
        float* outp = out + (size_t)(rowbase + rr) * H_;
#pragma unroll
        for (int i16 = 0; i16 < 4; i16++) {
            int i = i16 * 64 + ig * 4;
            const float* wh = w_out_high + i * 8;
            float4 s;
            s.x = b_out_high[i + 0]; s.y = b_out_high[i + 1];
            s.z = b_out_high[i + 2]; s.w = b_out_high[i + 3];
#pragma unroll
            for (int j = 0; j < 8; j++) {
                s.x += l[j] * wh[j];
                s.y += l[j] * wh[8 + j];
                s.z += l[j] * wh[16 + j];
                s.w += l[j] * wh[24 + j];
            }
            *(float4*)(outp + i) = s;
        }
    }
}

extern "C" void kernel_launch(void* const* d_in, const int* in_sizes, int n_in,
                              void* d_out, int out_size, void* d_ws, size_t ws_size,
                              hipStream_t stream) {
    const float* x          = (const float*)d_in[0];
    const float* w_qkv_low  = (const float*)d_in[1];
    const float* b_qkv_low  = (const float*)d_in[2];
    const float* w_qkv_high = (const float*)d_in[3];
    const float* b_qkv_high = (const float*)d_in[4];
    const float* w_out_low  = (const float*)d_in[5];
    const float* b_out_low  = (const float*)d_in[6];
    const float* w_out_high = (const float*)d_in[7];
    const float* b_out_high = (const float*)d_in[8];
    // d_in[9] adj_u, d_in[10] adj_v: unused (attn_reg_loss is the constant REGW/N)
    char* wsb = (char*)d_ws;
    float*    g_ql = (float*)(wsb);                           // 768 KB fp32 [24][8192]
    unsigned* kf_u = (unsigned*)(wsb + ((size_t)1 << 20));    // 4 MB  bf16 [4][8192][64]
    unsigned* v_u  = (unsigned*)(wsb + ((size_t)5 << 20));    // 4 MB
    float*    zg   = (float*)(wsb + ((size_t)9 << 20));       // 128 KB fp32 [8192][4]
    float*    kvp  = (float*)(wsb + ((size_t)10 << 20));      // 4 MB  fp32 [256][4096]
    float*    kvg  = (float*)(wsb + ((size_t)14 << 20));      // 256 KB fp32 [16][4096]
    float* out = (float*)d_out;

    ka_fused<<<512, 256, 0, stream>>>(x, w_qkv_low, b_qkv_low, w_qkv_high,
                                      b_qkv_high, g_ql, kf_u, v_u, zg);
    k2_kv<<<256, 256, 0, stream>>>(kf_u, v_u, kvp);
    k2b_reduce<<<256, 256, 0, stream>>>(kvp, kvg, out);
    k4_out<<<512, 256, 0, stream>>>(g_ql, w_qkv_high, b_qkv_high, zg, kvg,
                                    w_out_low, b_out_low, w_out_high,
                                    b_out_high, out);
}

// Round 8
// 132.938 us; speedup vs baseline: 1.2820x; 1.0295x over previous
//
#include <hip/hip_runtime.h>
#include <math.h>

// Problem constants
#define B_     4
#define N_     2048
#define H_     256
#define ROWS   8192    // B_*N_
#define EPS_   1e-8f
#define REGW   1e-5f
#define OUT_MAIN (ROWS*H_)   // 2097152

static __device__ __forceinline__ float elu1(float x) {
    return x > 0.f ? x + 1.f : __expf(x);
}

// fp32 pair -> packed bf16x2 (RNE)
static __device__ __forceinline__ unsigned pack_bf16x2(float a, float b) {
    unsigned ua = __float_as_uint(a), ub = __float_as_uint(b);
    ua = (ua + 0x7FFFu + ((ua >> 16) & 1u)) >> 16;
    ub = (ub + 0x7FFFu + ((ub >> 16) & 1u)) & 0xFFFF0000u;
    return ua | ub;
}
// packed bf16x2 -> fp32 pair (exact)
static __device__ __forceinline__ float2 unpack_bf16x2(unsigned u) {
    return make_float2(__uint_as_float(u << 16), __uint_as_float(u & 0xFFFF0000u));
}

// stage + transpose a 256-row w_high chunk [256][24] -> dst[k*260 + j]
static __device__ __forceinline__ void stage_whT(
    const float* __restrict__ wsrc, float* __restrict__ dst, int t)
{
#pragma unroll
    for (int i = 0; i < 6; i++) {
        int g = t + i * 256;
        float4 v4 = *(const float4*)(wsrc + g * 4);
        int e = g * 4, j = e / 24, k = e - j * 24;
        dst[(k + 0) * 260 + j] = v4.x;
        dst[(k + 1) * 260 + j] = v4.y;
        dst[(k + 2) * 260 + j] = v4.z;
        dst[(k + 3) * 260 + j] = v4.w;
    }
}

// ---------------------------------------------------------------------------
// ka_fused: 512 blocks x 256 thr; block = 16 rows. (unchanged from R7)
// ---------------------------------------------------------------------------
template<int MODE>  // 1 = k (elu + z), 2 = v (raw)
static __device__ __forceinline__ void chunk_compute(
    const float* __restrict__ buf, const float* __restrict__ qlT,
    const float* __restrict__ b_high, size_t rowbase,
    int wv, int c, unsigned* __restrict__ outu, float* __restrict__ zg)
{
    const int chunk = (MODE == 1) ? 1 : 2;
    float4 bh4 = *(const float4*)(b_high + chunk * 256 + c * 4);
    float4 a0 = bh4, a1 = bh4, a2 = bh4, a3 = bh4;
#pragma unroll
    for (int k = 0; k < 24; k++) {
        float4 w4 = *(const float4*)&buf[k * 260 + c * 4];
        float4 q4 = *(const float4*)&qlT[k * 16 + wv * 4];   // broadcast
        a0.x += q4.x * w4.x; a0.y += q4.x * w4.y; a0.z += q4.x * w4.z; a0.w += q4.x * w4.w;
        a1.x += q4.y * w4.x; a1.y += q4.y * w4.y; a1.z += q4.y * w4.z; a1.w += q4.y * w4.w;
        a2.x += q4.z * w4.x; a2.y += q4.z * w4.y; a2.z += q4.z * w4.z; a2.w += q4.z * w4.w;
        a3.x += q4.w * w4.x; a3.y += q4.w * w4.y; a3.z += q4.w * w4.z; a3.w += q4.w * w4.w;
    }
    const int h = c >> 4, dq = (c & 15) * 2;
    float4 aa[4] = {a0, a1, a2, a3};
    float zp[4];
#pragma unroll
    for (int rr = 0; rr < 4; rr++) {
        float4 a = aa[rr];
        if (MODE == 1) {
            a.x = elu1(a.x); a.y = elu1(a.y); a.z = elu1(a.z); a.w = elu1(a.w);
        }
        size_t row = rowbase + wv * 4 + rr;
        uint2 p;
        p.x = pack_bf16x2(a.x, a.y);
        p.y = pack_bf16x2(a.z, a.w);
        *(uint2*)(outu + ((size_t)h * ROWS + row) * 32 + dq) = p;
        if (MODE == 1) zp[rr] = a.x + a.y + a.z + a.w;
    }
    if (MODE == 1) {
#pragma unroll
        for (int rr = 0; rr < 4; rr++) {
            float s = zp[rr];
            s += __shfl_xor(s, 1, 16);
            s += __shfl_xor(s, 2, 16);
            s += __shfl_xor(s, 4, 16);
            s += __shfl_xor(s, 8, 16);
            zp[rr] = s;
        }
        if ((c & 15) == 0) {
#pragma unroll
            for (int rr = 0; rr < 4; rr++)
                zg[(rowbase + wv * 4 + rr) * 4 + h] = 1.f / (zp[rr] + EPS_);
        }
    }
}

__global__ __launch_bounds__(256) void ka_fused(
    const float* __restrict__ x, const float* __restrict__ w_low,
    const float* __restrict__ b_low, const float* __restrict__ w_high,
    const float* __restrict__ b_high, float* __restrict__ g_ql,
    unsigned* __restrict__ kf_u, unsigned* __restrict__ v_u,
    float* __restrict__ zg)
{
    __shared__ float bufA[24 * 260];
    __shared__ float bufB[24 * 260];
    __shared__ float qlT[24 * 16];

    const int t = threadIdx.x;
    const size_t rowbase = (size_t)blockIdx.x * 16;
    const int rb = t >> 4, c4 = t & 15;   // phase-b ids
    const int wv = t >> 6, c  = t & 63;   // phase-c ids

    // stage w_low [24][256] -> bufA[j*260+k] (straight copy)
#pragma unroll
    for (int i = 0; i < 6; i++) {
        int g = t + i * 256;
        int j = g >> 6, k = (g & 63) * 4;
        *(float4*)&bufA[j * 260 + k] = *(const float4*)(w_low + g * 4);
    }
    // stage + transpose w_high chunk1 (k-weights) -> bufB
    stage_whT(w_high + 6144, bufB, t);
    // x slice into registers (interleaved k-slices, coalesced)
    float4 xr[4];
#pragma unroll
    for (int i = 0; i < 4; i++)
        xr[i] = *(const float4*)(x + (rowbase + rb) * H_ + i * 64 + c4 * 4);
    __syncthreads();   // B1

    // phase b -> ql[24] (all lanes of a row-group hold the full vector)
    {
        float ql[24];
#pragma unroll
        for (int j = 0; j < 24; j++) {
            float s = 0.f;
#pragma unroll
            for (int i = 0; i < 4; i++) {
                float4 w4 = *(const float4*)&bufA[j * 260 + i * 64 + c4 * 4];
                s += xr[i].x * w4.x + xr[i].y * w4.y + xr[i].z * w4.z + xr[i].w * w4.w;
            }
            s += __shfl_xor(s, 1, 16);
            s += __shfl_xor(s, 2, 16);
            s += __shfl_xor(s, 4, 16);
            s += __shfl_xor(s, 8, 16);
            ql[j] = s + b_low[j];
        }
        // global ql col-major [k][row]: 64B runs per (k, rowgroup)
        size_t row = rowbase + rb;
        g_ql[(size_t)c4 * ROWS + row] = ql[c4];
        if (c4 < 8) g_ql[(size_t)(16 + c4) * ROWS + row] = ql[16 + c4];
        qlT[c4 * 16 + rb] = ql[c4];
        if (c4 < 8) qlT[(16 + c4) * 16 + rb] = ql[16 + c4];
    }
    __syncthreads();   // B2: qlT visible; bufA free

    stage_whT(w_high + 12288, bufA, t);     // v-weights -> bufA (overlaps kf)
    chunk_compute<1>(bufB, qlT, b_high, rowbase, wv, c, kf_u, zg);
    __syncthreads();   // B3

    chunk_compute<2>(bufA, qlT, b_high, rowbase, wv, c, v_u, zg);
}

// ---------------------------------------------------------------------------
// k2_kv: partial kv over 128-row chunks. Grid 256 = b*64 + h*16 + ch.
// (unchanged from R7)
// ---------------------------------------------------------------------------
__global__ __launch_bounds__(256) void k2_kv(
    const unsigned* __restrict__ kfu, const unsigned* __restrict__ vu,
    float* __restrict__ kvp)
{
    __shared__ float kfs[128 * 68];
    __shared__ float vss[128 * 68];
    const int blk = blockIdx.x;
    const int b = blk >> 6, h = (blk >> 4) & 3, ch = blk & 15;
    const int t = threadIdx.x;
    const size_t base_u = ((size_t)h * ROWS + (size_t)b * N_ + ch * 128) * 32;
#pragma unroll
    for (int i = 0; i < 4; i++) {
        int g = t + i * 256;
        int r = g >> 3, q = g & 7;
        uint4 ku = *(const uint4*)(kfu + base_u + r * 32 + q * 4);
        uint4 vv4 = *(const uint4*)(vu + base_u + r * 32 + q * 4);
        float2 f0 = unpack_bf16x2(ku.x), f1 = unpack_bf16x2(ku.y);
        float2 f2 = unpack_bf16x2(ku.z), f3 = unpack_bf16x2(ku.w);
        *(float4*)&kfs[r * 68 + q * 8 + 0] = make_float4(f0.x, f0.y, f1.x, f1.y);
        *(float4*)&kfs[r * 68 + q * 8 + 4] = make_float4(f2.x, f2.y, f3.x, f3.y);
        f0 = unpack_bf16x2(vv4.x); f1 = unpack_bf16x2(vv4.y);
        f2 = unpack_bf16x2(vv4.z); f3 = unpack_bf16x2(vv4.w);
        *(float4*)&vss[r * 68 + q * 8 + 0] = make_float4(f0.x, f0.y, f1.x, f1.y);
        *(float4*)&vss[r * 68 + q * 8 + 4] = make_float4(f2.x, f2.y, f3.x, f3.y);
    }
    __syncthreads();
    const int d0 = (t >> 4) * 4, e0 = (t & 15) * 4;
    float4 a0 = {0,0,0,0}, a1 = {0,0,0,0}, a2 = {0,0,0,0}, a3 = {0,0,0,0};
    for (int i = 0; i < 128; i++) {
        float4 kk = *(const float4*)&kfs[i * 68 + d0];
        float4 v4 = *(const float4*)&vss[i * 68 + e0];
        a0.x += kk.x * v4.x; a0.y += kk.x * v4.y; a0.z += kk.x * v4.z; a0.w += kk.x * v4.w;
        a1.x += kk.y * v4.x; a1.y += kk.y * v4.y; a1.z += kk.y * v4.z; a1.w += kk.y * v4.w;
        a2.x += kk.z * v4.x; a2.y += kk.z * v4.y; a2.z += kk.z * v4.z; a2.w += kk.z * v4.w;
        a3.x += kk.w * v4.x; a3.y += kk.w * v4.y; a3.z += kk.w * v4.z; a3.w += kk.w * v4.w;
    }
    float* outp = kvp + (size_t)blk * 4096;
    *(float4*)(outp + (d0 + 0) * 64 + e0) = a0;
    *(float4*)(outp + (d0 + 1) * 64 + e0) = a1;
    *(float4*)(outp + (d0 + 2) * 64 + e0) = a2;
    *(float4*)(outp + (d0 + 3) * 64 + e0) = a3;
}

// ---------------------------------------------------------------------------
// k2b: reduce 16 partials -> kv[bh][d*64+e]; write constant reg-loss
// (softmax rows sum to 1 => mean|attn| == 1/N; adj_u/adj_v cannot change it).
// Grid 256 x 256. (unchanged from R7)
// ---------------------------------------------------------------------------
__global__ __launch_bounds__(256) void k2b_reduce(
    const float* __restrict__ kvp, float* __restrict__ kvg,
    float* __restrict__ out)
{
    const int blk = blockIdx.x, t = threadIdx.x;
    const int bh = blk >> 4;
    const size_t pbase = (size_t)((bh >> 2) * 64 + (bh & 3) * 16);
    const int idx = (blk & 15) * 256 + t;
    float s = 0.f;
#pragma unroll
    for (int c = 0; c < 16; c++)
        s += kvp[(pbase + c) * 4096 + idx];
    kvg[(size_t)bh * 4096 + idx] = s;
    if (blk == 0 && t == 0)
        out[OUT_MAIN] = REGW / (float)N_;   // 4.8828125e-9
}

// ---------------------------------------------------------------------------
// k4_out (REWRITTEN): 512 blocks x 256 thr; block = 16 rows.
// Lane = e-f4 column c (head h = c>>4); wave = 4-row group. Main GEMM:
// 64 global kv loads/lane (every inst = 64 distinct f4s, 4x256B coalesced
// runs), qf from per-head-padded LDS tile [h][16][68] (head stride 1092 ->
// the 4 broadcast addresses hit distinct bank-quads). lin aliases bufW
// (dead after qf recompute) -> LDS 44.7 KB -> 3 blocks/CU, 12 waves.
// ---------------------------------------------------------------------------
__global__ __launch_bounds__(256) void k4_out(
    const float* __restrict__ g_ql, const float* __restrict__ w_high,
    const float* __restrict__ b_high, const float* __restrict__ zg,
    const float* __restrict__ kvg,
    const float* __restrict__ w_out_low, const float* __restrict__ b_out_low,
    const float* __restrict__ w_out_high, const float* __restrict__ b_out_high,
    float* __restrict__ out)
{
    __shared__ float bufW[24 * 260];   // w_high q^T; rows 0..15 reused as lin
    __shared__ float qfs[4 * 1092];    // [h][row 16][stride 68]
    __shared__ float qlT[24 * 16];
    __shared__ float lows[16 * 8];
    __shared__ float zs[64];
    float* lin = bufW;                 // alias: lin[16][260]

    const int t = threadIdx.x, blk = blockIdx.x;
    const int rowbase = blk * 16;
    const int b = blk >> 7;
    const float* kvb = kvg + (size_t)b * 4 * 4096;

    stage_whT(w_high, bufW, t);            // q-weights
    // stage qlT: 384 entries with 256 threads
    {
        int k = t >> 4, r = t & 15;
        qlT[t] = g_ql[(size_t)k * ROWS + rowbase + r];
        if (t < 128) {
            int idx2 = 256 + t;
            int k2 = idx2 >> 4, r2 = idx2 & 15;
            qlT[idx2] = g_ql[(size_t)k2 * ROWS + rowbase + r2];
        }
    }
    if (t < 64) zs[t] = zg[(size_t)rowbase * 4 + t];
    __syncthreads();

    const int wv = t >> 6, c = t & 63;
    const int h = c >> 4, e4 = c & 15;

    // phase 1: recompute qf rows wv*4..+3, cols j = c*4..+3 -> qfs[h][row][dl]
    {
        float4 bh4 = *(const float4*)(b_high + c * 4);
        float4 a0 = bh4, a1 = bh4, a2 = bh4, a3 = bh4;
#pragma unroll
        for (int k = 0; k < 24; k++) {
            float4 w4 = *(const float4*)&bufW[k * 260 + c * 4];
            float4 q4 = *(const float4*)&qlT[k * 16 + wv * 4];
            a0.x += q4.x * w4.x; a0.y += q4.x * w4.y; a0.z += q4.x * w4.z; a0.w += q4.x * w4.w;
            a1.x += q4.y * w4.x; a1.y += q4.y * w4.y; a1.z += q4.y * w4.z; a1.w += q4.y * w4.w;
            a2.x += q4.z * w4.x; a2.y += q4.z * w4.y; a2.z += q4.z * w4.z; a2.w += q4.z * w4.w;
            a3.x += q4.w * w4.x; a3.y += q4.w * w4.y; a3.z += q4.w * w4.z; a3.w += q4.w * w4.w;
        }
        float4 aa[4] = {a0, a1, a2, a3};
#pragma unroll
        for (int rr = 0; rr < 4; rr++) {
            float4 a = aa[rr];
            a.x = elu1(a.x); a.y = elu1(a.y); a.z = elu1(a.z); a.w = elu1(a.w);
            *(float4*)&qfs[h * 1092 + (wv * 4 + rr) * 68 + e4 * 4] = a;
        }
    }
    __syncthreads();   // qfs ready; bufW dead -> lin may be written

    // phase 2: lin[row][c*4..+3] = z * sum_d qf[row][h*64+d] * kv[h][d][e]
    {
        float4 acc[4] = {{0,0,0,0},{0,0,0,0},{0,0,0,0},{0,0,0,0}};
        const float* kvh = kvb + h * 4096 + e4 * 4;
        const float* qrow = &qfs[h * 1092 + (wv * 4) * 68];
#pragma unroll
        for (int d4 = 0; d4 < 16; d4++) {
            float4 k0 = *(const float4*)(kvh + (d4 * 4 + 0) * 64);
            float4 k1 = *(const float4*)(kvh + (d4 * 4 + 1) * 64);
            float4 k2 = *(const float4*)(kvh + (d4 * 4 + 2) * 64);
            float4 k3 = *(const float4*)(kvh + (d4 * 4 + 3) * 64);
#pragma unroll
            for (int rr = 0; rr < 4; rr++) {
                float4 qa = *(const float4*)(qrow + rr * 68 + d4 * 4);
                acc[rr].x += qa.x * k0.x + qa.y * k1.x + qa.z * k2.x + qa.w * k3.x;
                acc[rr].y += qa.x * k0.y + qa.y * k1.y + qa.z * k2.y + qa.w * k3.y;
                acc[rr].z += qa.x * k0.z + qa.y * k1.z + qa.z * k2.z + qa.w * k3.z;
                acc[rr].w += qa.x * k0.w + qa.y * k1.w + qa.z * k2.w + qa.w * k3.w;
            }
        }
#pragma unroll
        for (int rr = 0; rr < 4; rr++) {
            float zv = zs[(wv * 4 + rr) * 4 + h];
            *(float4*)&lin[(wv * 4 + rr) * 260 + c * 4] =
                make_float4(acc[rr].x * zv, acc[rr].y * zv,
                            acc[rr].z * zv, acc[rr].w * zv);
        }
    }
    __syncthreads();

    // phase 3: low projection (128 threads; 8-lane broadcast reads)
    if (t < 128) {
        int rr = t >> 3, j = t & 7;
        float a = b_out_low[j];
        const float4* wj = (const float4*)(w_out_low + j * H_);
#pragma unroll
        for (int kq = 0; kq < 64; kq++) {
            float4 l4 = *(const float4*)&lin[rr * 260 + kq * 4];
            float4 w4 = wj[kq];
            a += l4.x * w4.x + l4.y * w4.y + l4.z * w4.z + l4.w * w4.w;
        }
        lows[rr * 8 + j] = a;
    }
    __syncthreads();

    // phase 4: high projection, coalesced f4 stores
    {
        int rr = t >> 4, ig = t & 15;
        float l[8];
#pragma unroll
        for (int j = 0; j < 8; j++) l[j] = lows[rr * 8 + j];
        float* outp = out + (size_t)(rowbase + rr) * H_;
#pragma unroll
        for (int i16 = 0; i16 < 4; i16++) {
            int i = i16 * 64 + ig * 4;
            const float* wh = w_out_high + i * 8;
            float4 s;
            s.x = b_out_high[i + 0]; s.y = b_out_high[i + 1];
            s.z = b_out_high[i + 2]; s.w = b_out_high[i + 3];
#pragma unroll
            for (int j = 0; j < 8; j++) {
                s.x += l[j] * wh[j];
                s.y += l[j] * wh[8 + j];
                s.z += l[j] * wh[16 + j];
                s.w += l[j] * wh[24 + j];
            }
            *(float4*)(outp + i) = s;
        }
    }
}

extern "C" void kernel_launch(void* const* d_in, const int* in_sizes, int n_in,
                              void* d_out, int out_size, void* d_ws, size_t ws_size,
                              hipStream_t stream) {
    const float* x          = (const float*)d_in[0];
    const float* w_qkv_low  = (const float*)d_in[1];
    const float* b_qkv_low  = (const float*)d_in[2];
    const float* w_qkv_high = (const float*)d_in[3];
    const float* b_qkv_high = (const float*)d_in[4];
    const float* w_out_low  = (const float*)d_in[5];
    const float* b_out_low  = (const float*)d_in[6];
    const float* w_out_high = (const float*)d_in[7];
    const float* b_out_high = (const float*)d_in[8];
    // d_in[9] adj_u, d_in[10] adj_v: unused (attn_reg_loss is the constant REGW/N)
    char* wsb = (char*)d_ws;
    float*    g_ql = (float*)(wsb);                           // 768 KB fp32 [24][8192]
    unsigned* kf_u = (unsigned*)(wsb + ((size_t)1 << 20));    // 4 MB  bf16 [4][8192][64]
    unsigned* v_u  = (unsigned*)(wsb + ((size_t)5 << 20));    // 4 MB
    float*    zg   = (float*)(wsb + ((size_t)9 << 20));       // 128 KB fp32 [8192][4]
    float*    kvp  = (float*)(wsb + ((size_t)10 << 20));      // 4 MB  fp32 [256][4096]
    float*    kvg  = (float*)(wsb + ((size_t)14 << 20));      // 256 KB fp32 [16][4096]
    float* out = (float*)d_out;

    ka_fused<<<512, 256, 0, stream>>>(x, w_qkv_low, b_qkv_low, w_qkv_high,
                                      b_qkv_high, g_ql, kf_u, v_u, zg);
    k2_kv<<<256, 256, 0, stream>>>(kf_u, v_u, kvp);
    k2b_reduce<<<256, 256, 0, stream>>>(kvp, kvg, out);
    k4_out<<<512, 256, 0, stream>>>(g_ql, w_qkv_high, b_qkv_high, zg, kvg,
                                    w_out_low, b_out_low, w_out_high,
                                    b_out_high, out);
}